// Round 1
// baseline (7952.849 us; speedup 1.0000x reference)
//
#include <hip/hip_runtime.h>
#include <hip/hip_bf16.h>
#include <math.h>

// ---------------- problem constants ----------------
#define BDIM 32
#define HDIM 56
#define WDIM 56
#define CDIM 384
#define NHEAD 12
#define WSZ 14
#define SSZ 7
#define LDIM (HDIM*WDIM)        // 3136
#define NTOK (WSZ*WSZ)          // 196
#define HDHEAD (CDIM/NHEAD)     // 32
#define HIDDIM (4*CDIM)         // 1536
#define NWIN 16
#define BWIN (BDIM*NWIN)        // 512
#define MROWS (BDIM*LDIM)       // 100352 == BWIN*NTOK
#define EPSLN 1e-5f
#define ATTSCALE 0.17677669529663687f   // 32^-0.5

typedef __hip_bfloat16 bf16;

// ---------------- LN (+optional shift-roll + window partition) ----------------
// one block (128 threads) per row; WIN=true maps (b,h,w) -> windowed row of xw
template<bool WIN>
__global__ __launch_bounds__(128) void k_ln(const float* __restrict__ xin,
    const float* __restrict__ gw, const float* __restrict__ gb,
    bf16* __restrict__ out)
{
  int r = blockIdx.x;
  int t = threadIdx.x;
  const float* xp = xin + (size_t)r * CDIM;
  float v0 = xp[t], v1 = xp[t+128], v2 = xp[t+256];
  float s  = v0+v1+v2;
  float ss = v0*v0 + v1*v1 + v2*v2;
  #pragma unroll
  for (int o = 32; o > 0; o >>= 1) { s += __shfl_down(s, o); ss += __shfl_down(ss, o); }
  __shared__ float red[4];
  if ((t & 63) == 0) { red[(t>>6)*2] = s; red[(t>>6)*2+1] = ss; }
  __syncthreads();
  float mean = (red[0]+red[2]) * (1.0f/CDIM);
  float var  = (red[1]+red[3]) * (1.0f/CDIM) - mean*mean;
  float rstd = rsqrtf(var + EPSLN);

  size_t orow;
  if (WIN) {
    int b = r / LDIM, l = r % LDIM;
    int h = l / WDIM, w = l % WDIM;
    // xs[h'] = xn[(h'+7)%56]  =>  dest h' = (h-7) mod 56
    int h2 = (h + HDIM - SSZ) % HDIM, w2 = (w + WDIM - SSZ) % WDIM;
    int wh = h2 / WSZ, ii = h2 % WSZ, ww = w2 / WSZ, jj = w2 % WSZ;
    int b_ = b*NWIN + wh*4 + ww;
    int n  = ii*WSZ + jj;
    orow = ((size_t)b_*NTOK + n) * CDIM;
  } else {
    orow = (size_t)r * CDIM;
  }
  out[orow+t]     = __float2bfloat16((v0-mean)*rstd*gw[t]     + gb[t]);
  out[orow+t+128] = __float2bfloat16((v1-mean)*rstd*gw[t+128] + gb[t+128]);
  out[orow+t+256] = __float2bfloat16((v2-mean)*rstd*gw[t+256] + gb[t+256]);
}

// ---------------- generic fp32 tiled GEMM: out = A(bf16,MxK) @ Wt(fp32,NCxK)^T ----------------
// EPI 0: qkv scatter (+SCALE on q)   EPI 1: proj + window-reverse + residual -> x2 (f32)
// EPI 2: fc1 + exact gelu -> bf16    EPI 3: fc2 + bias + x2 residual -> f32 d_out
template<int KD, int NC, int EPI>
__global__ __launch_bounds__(256) void k_gemm(
    const bf16* __restrict__ A, const float* __restrict__ Wt,
    const float* __restrict__ bias, const float* __restrict__ aux,
    float* __restrict__ outf, bf16* __restrict__ outb)
{
  __shared__ float As[16][65];
  __shared__ float Bs[16][65];
  int tid = threadIdx.x;
  int tr = tid >> 4, tc = tid & 15;
  int row0 = blockIdx.y * 64, col0 = blockIdx.x * 64;
  float acc[4][4] = {};

  for (int k0 = 0; k0 < KD; k0 += 16) {
    #pragma unroll
    for (int i = 0; i < 2; i++) {              // A tile: 64x16 bf16 (512 pairs)
      int p = tid + i*256;
      int m = p >> 3, kp = (p & 7) * 2;
      const bf16* ap = A + (size_t)(row0+m)*KD + (k0+kp);
      As[kp][m]   = __bfloat162float(ap[0]);
      As[kp+1][m] = __bfloat162float(ap[1]);
    }
    #pragma unroll
    for (int i = 0; i < 4; i++) {              // B tile: Bs[k][n] = Wt[col][k]
      int p = tid + i*256;
      int nn = p >> 4, kk = p & 15;
      Bs[kk][nn] = Wt[(size_t)(col0+nn)*KD + (k0+kk)];
    }
    __syncthreads();
    #pragma unroll
    for (int kk = 0; kk < 16; kk++) {
      float a0=As[kk][tr*4+0], a1=As[kk][tr*4+1], a2=As[kk][tr*4+2], a3=As[kk][tr*4+3];
      float b0=Bs[kk][tc*4+0], b1=Bs[kk][tc*4+1], b2=Bs[kk][tc*4+2], b3=Bs[kk][tc*4+3];
      acc[0][0]+=a0*b0; acc[0][1]+=a0*b1; acc[0][2]+=a0*b2; acc[0][3]+=a0*b3;
      acc[1][0]+=a1*b0; acc[1][1]+=a1*b1; acc[1][2]+=a1*b2; acc[1][3]+=a1*b3;
      acc[2][0]+=a2*b0; acc[2][1]+=a2*b1; acc[2][2]+=a2*b2; acc[2][3]+=a2*b3;
      acc[3][0]+=a3*b0; acc[3][1]+=a3*b1; acc[3][2]+=a3*b2; acc[3][3]+=a3*b3;
    }
    __syncthreads();
  }

  int rbase = row0 + tr*4, cbase = col0 + tc*4;
  if constexpr (EPI == 0) {
    const size_t QKVSTRIDE = (size_t)BWIN*NHEAD*NTOK*HDHEAD;
    #pragma unroll
    for (int i = 0; i < 4; i++) {
      int r = rbase + i; int b_ = r / NTOK, n = r % NTOK;
      #pragma unroll
      for (int j = 0; j < 4; j++) {
        int c = cbase + j;
        float val = acc[i][j] + bias[c];
        int which = c / CDIM, rem = c - which*CDIM;
        int hh = rem >> 5, dd = rem & 31;
        if (which == 0) val *= ATTSCALE;
        outb[(size_t)which*QKVSTRIDE + (((size_t)b_*NHEAD+hh)*NTOK+n)*HDHEAD + dd]
            = __float2bfloat16(val);
      }
    }
  } else if constexpr (EPI == 1) {
    #pragma unroll
    for (int i = 0; i < 4; i++) {
      int r = rbase + i; int b_ = r / NTOK, n = r % NTOK;
      int b = b_ >> 4, wi = b_ & 15, wh = wi >> 2, ww = wi & 3;
      int ii = n / WSZ, jj = n % WSZ;
      int hh = (wh*WSZ + ii + SSZ) % HDIM;
      int wc = (ww*WSZ + jj + SSZ) % WDIM;
      size_t rr = ((size_t)b*LDIM + hh*WDIM + wc) * CDIM;
      #pragma unroll
      for (int j = 0; j < 4; j++) {
        int c = cbase + j;
        outf[rr+c] = aux[rr+c] + acc[i][j] + bias[c];
      }
    }
  } else if constexpr (EPI == 2) {
    #pragma unroll
    for (int i = 0; i < 4; i++) {
      int r = rbase + i;
      #pragma unroll
      for (int j = 0; j < 4; j++) {
        int c = cbase + j;
        float val = acc[i][j] + bias[c];
        val = 0.5f * val * (1.0f + erff(val * 0.70710678118654752f));
        outb[(size_t)r*NC + c] = __float2bfloat16(val);
      }
    }
  } else {
    #pragma unroll
    for (int i = 0; i < 4; i++) {
      int r = rbase + i;
      #pragma unroll
      for (int j = 0; j < 4; j++) {
        int c = cbase + j;
        outf[(size_t)r*CDIM + c] = acc[i][j] + bias[c] + aux[(size_t)r*CDIM + c];
      }
    }
  }
}

// ---------------- fused window attention: one block per (window, head) ----------------
__global__ __launch_bounds__(256) void k_attn(const bf16* __restrict__ q,
    const bf16* __restrict__ k, const bf16* __restrict__ v,
    const float* __restrict__ rt, bf16* __restrict__ out)
{
  int blk = blockIdx.x;               // b_*NHEAD + head
  int b_ = blk / NHEAD, head = blk % NHEAD;
  __shared__ float Ks[NTOK][HDHEAD];
  __shared__ float Vs[NTOK][HDHEAD];
  __shared__ float tabH[729];
  __shared__ float tabR[729];
  __shared__ int   regv[NTOK];
  int tid = threadIdx.x;

  const bf16* kp = k + (size_t)blk*NTOK*HDHEAD;
  const bf16* vp = v + (size_t)blk*NTOK*HDHEAD;
  for (int e = tid; e < NTOK*HDHEAD; e += 256) {
    Ks[e>>5][e&31] = __bfloat162float(kp[e]);
    Vs[e>>5][e&31] = __bfloat162float(vp[e]);
  }
  for (int e = tid; e < 729; e += 256) {
    tabH[e] = rt[e*2*NHEAD + head];
    tabR[e] = rt[e*2*NHEAD + NHEAD + head];
  }
  {
    int wi = b_ & 15, wh = wi >> 2, ww = wi & 3;
    for (int e = tid; e < NTOK; e += 256) {
      int i = e / WSZ, j = e % WSZ;
      int ha = wh*WSZ + i, wa = ww*WSZ + j;
      int rh = ha < (HDIM-WSZ) ? 0 : (ha < (HDIM-SSZ) ? 1 : 2);
      int rw = wa < (WDIM-WSZ) ? 0 : (wa < (WDIM-SSZ) ? 1 : 2);
      regv[e] = rh*3 + rw;
    }
  }
  __syncthreads();
  if (tid >= NTOK) return;
  int n = tid;

  float qr[32];
  const bf16* qp = q + ((size_t)blk*NTOK + n)*HDHEAD;
  #pragma unroll
  for (int d = 0; d < 32; d++) qr[d] = __bfloat162float(qp[d]);
  int ni = n / WSZ, nj = n % WSZ;
  int myreg = regv[n];

  // pass 1: online max / sum (scores recomputed in pass 2)
  float mmax = -1e30f, lsum = 0.f;
  for (int m = 0; m < NTOK; m++) {
    float s = 0.f;
    #pragma unroll
    for (int d4 = 0; d4 < 8; d4++) {
      float4 kv = ((const float4*)Ks[m])[d4];
      s += qr[d4*4+0]*kv.x + qr[d4*4+1]*kv.y + qr[d4*4+2]*kv.z + qr[d4*4+3]*kv.w;
    }
    int dh = ni - m/WSZ + 13, dw = nj - m%WSZ + 13;
    s += tabH[dh*27 + dw];
    if (regv[m] != myreg) s -= 100.f;
    if (s > mmax) { lsum *= __expf(mmax - s); mmax = s; }
    lsum += __expf(s - mmax);
  }
  float inv = 1.f / lsum;

  // pass 2: P*V with post-softmax rscale
  float accd[32] = {};
  for (int m = 0; m < NTOK; m++) {
    float s = 0.f;
    #pragma unroll
    for (int d4 = 0; d4 < 8; d4++) {
      float4 kv = ((const float4*)Ks[m])[d4];
      s += qr[d4*4+0]*kv.x + qr[d4*4+1]*kv.y + qr[d4*4+2]*kv.z + qr[d4*4+3]*kv.w;
    }
    int dh = ni - m/WSZ + 13, dw = nj - m%WSZ + 13;
    int idx = dh*27 + dw;
    s += tabH[idx];
    if (regv[m] != myreg) s -= 100.f;
    float p = __expf(s - mmax) * tabR[idx] * inv;
    #pragma unroll
    for (int d4 = 0; d4 < 8; d4++) {
      float4 vv = ((const float4*)Vs[m])[d4];
      accd[d4*4+0] += p*vv.x; accd[d4*4+1] += p*vv.y;
      accd[d4*4+2] += p*vv.z; accd[d4*4+3] += p*vv.w;
    }
  }

  // write (b_, n, head*32+d) so proj GEMM reads a plain row-major matrix
  bf16* op = out + ((size_t)b_*NTOK + n)*CDIM + head*HDHEAD;
  #pragma unroll
  for (int d = 0; d < 32; d++) op[d] = __float2bfloat16(accd[d]);
}

// ---------------- launch ----------------
extern "C" void kernel_launch(void* const* d_in, const int* in_sizes, int n_in,
                              void* d_out, int out_size, void* d_ws, size_t ws_size,
                              hipStream_t stream)
{
  const float* x      = (const float*)d_in[0];
  const float* n1w    = (const float*)d_in[1];
  const float* n1b    = (const float*)d_in[2];
  const float* qkv_w  = (const float*)d_in[3];
  const float* qkv_b  = (const float*)d_in[4];
  const float* proj_w = (const float*)d_in[5];
  const float* proj_b = (const float*)d_in[6];
  const float* rt     = (const float*)d_in[7];
  const float* n2w    = (const float*)d_in[8];
  const float* n2b    = (const float*)d_in[9];
  const float* fc1_w  = (const float*)d_in[10];
  const float* fc1_b  = (const float*)d_in[11];
  const float* fc2_w  = (const float*)d_in[12];
  const float* fc2_b  = (const float*)d_in[13];

  char* ws = (char*)d_ws;
  const size_t SZ_BF = (size_t)MROWS * CDIM * 2;   // 77,070,336 B
  // arena: [0,1SZ) xw -> attnout | [1SZ,4SZ) qkv -> x2(f32,2SZ)+hln(1SZ) | [4SZ,8SZ) hid
  bf16*  xw      = (bf16*)ws;
  bf16*  qkv     = (bf16*)(ws + SZ_BF);
  bf16*  attnout = (bf16*)ws;
  float* x2      = (float*)(ws + SZ_BF);
  bf16*  hln     = (bf16*)(ws + 3*SZ_BF);
  bf16*  hid     = (bf16*)(ws + 4*SZ_BF);
  const size_t QKVSTRIDE = (size_t)BWIN*NHEAD*NTOK*HDHEAD;

  k_ln<true><<<MROWS, 128, 0, stream>>>(x, n1w, n1b, xw);
  k_gemm<CDIM, 3*CDIM, 0><<<dim3((3*CDIM)/64, MROWS/64), 256, 0, stream>>>(
      xw, qkv_w, qkv_b, nullptr, nullptr, qkv);
  k_attn<<<BWIN*NHEAD, 256, 0, stream>>>(
      qkv, qkv + QKVSTRIDE, qkv + 2*QKVSTRIDE, rt, attnout);
  k_gemm<CDIM, CDIM, 1><<<dim3(CDIM/64, MROWS/64), 256, 0, stream>>>(
      attnout, proj_w, proj_b, x, x2, nullptr);
  k_ln<false><<<MROWS, 128, 0, stream>>>(x2, n2w, n2b, hln);
  k_gemm<CDIM, HIDDIM, 2><<<dim3(HIDDIM/64, MROWS/64), 256, 0, stream>>>(
      hln, fc1_w, fc1_b, nullptr, nullptr, hid);
  k_gemm<HIDDIM, CDIM, 3><<<dim3(CDIM/64, MROWS/64), 256, 0, stream>>>(
      hid, fc2_w, fc2_b, x2, (float*)d_out, nullptr);
}

// Round 3
// 2214.689 us; speedup vs baseline: 3.5910x; 3.5910x over previous
//
#include <hip/hip_runtime.h>
#include <hip/hip_bf16.h>
#include <math.h>

// ---------------- problem constants ----------------
#define BDIM 32
#define HDIM 56
#define WDIM 56
#define CDIM 384
#define NHEAD 12
#define WSZ 14
#define SSZ 7
#define LDIM (HDIM*WDIM)        // 3136
#define NTOK (WSZ*WSZ)          // 196
#define HDHEAD (CDIM/NHEAD)     // 32
#define HIDDIM (4*CDIM)         // 1536
#define NWIN 16
#define BWIN (BDIM*NWIN)        // 512
#define MROWS (BDIM*LDIM)       // 100352 == BWIN*NTOK
#define EPSLN 1e-5f
#define ATTSCALE 0.17677669529663687f   // 32^-0.5

typedef __hip_bfloat16 bf16;
typedef __attribute__((ext_vector_type(8))) short bf16x8;   // 8 bf16 = 4 VGPRs
typedef __attribute__((ext_vector_type(4))) float f32x4;

// async global->LDS, 16B per lane, wave-uniform LDS base
#define ASYNC16(gp, lp) __builtin_amdgcn_global_load_lds( \
    (__attribute__((address_space(1))) void*)(gp),        \
    (__attribute__((address_space(3))) void*)(lp), 16, 0, 0)

// ---------------- fp32 -> bf16 weight convert ----------------
__global__ __launch_bounds__(256) void k_cvt(const float* __restrict__ in,
                                             bf16* __restrict__ out, int n)
{
  int i = blockIdx.x * 256 + threadIdx.x;
  if (i < n) out[i] = __float2bfloat16(in[i]);
}

// ---------------- LN (+optional shift-roll + window partition) ----------------
template<bool WIN>
__global__ __launch_bounds__(128) void k_ln(const float* __restrict__ xin,
    const float* __restrict__ gw, const float* __restrict__ gb,
    bf16* __restrict__ out)
{
  int r = blockIdx.x;
  int t = threadIdx.x;
  const float* xp = xin + (size_t)r * CDIM;
  float v0 = xp[t], v1 = xp[t+128], v2 = xp[t+256];
  float s  = v0+v1+v2;
  float ss = v0*v0 + v1*v1 + v2*v2;
  #pragma unroll
  for (int o = 32; o > 0; o >>= 1) { s += __shfl_down(s, o); ss += __shfl_down(ss, o); }
  __shared__ float red[4];
  if ((t & 63) == 0) { red[(t>>6)*2] = s; red[(t>>6)*2+1] = ss; }
  __syncthreads();
  float mean = (red[0]+red[2]) * (1.0f/CDIM);
  float var  = (red[1]+red[3]) * (1.0f/CDIM) - mean*mean;
  float rstd = rsqrtf(var + EPSLN);

  size_t orow;
  if (WIN) {
    int b = r / LDIM, l = r % LDIM;
    int h = l / WDIM, w = l % WDIM;
    int h2 = (h + HDIM - SSZ) % HDIM, w2 = (w + WDIM - SSZ) % WDIM;
    int wh = h2 / WSZ, ii = h2 % WSZ, ww = w2 / WSZ, jj = w2 % WSZ;
    int b_ = b*NWIN + wh*4 + ww;
    int n  = ii*WSZ + jj;
    orow = ((size_t)b_*NTOK + n) * CDIM;
  } else {
    orow = (size_t)r * CDIM;
  }
  out[orow+t]     = __float2bfloat16((v0-mean)*rstd*gw[t]     + gb[t]);
  out[orow+t+128] = __float2bfloat16((v1-mean)*rstd*gw[t+128] + gb[t+128]);
  out[orow+t+256] = __float2bfloat16((v2-mean)*rstd*gw[t+256] + gb[t+256]);
}

// ---------------- MFMA GEMM: C = A(bf16,MxK) @ Wb(bf16,NCxK)^T ----------------
// m97 structure: 128x128 tile, BK=32, 4 waves (2x2), 16x16x32 bf16 MFMA, 4x4 frags.
// EPI 0: qkv scatter (+SCALE on q)   EPI 1: proj + window-reverse + residual -> f32
// EPI 2: fc1 + exact gelu -> bf16    EPI 3: fc2 + bias + residual -> f32
template<int KD, int EPI>
__global__ __launch_bounds__(256) void k_mgemm(
    const bf16* __restrict__ A, const bf16* __restrict__ Wb,
    const float* __restrict__ bias, const float* __restrict__ aux,
    float* __restrict__ outf, bf16* __restrict__ outb)
{
  __shared__ short As[128*32];   // [row][k] linear, 8 KB
  __shared__ short Bs[128*32];   // [col][k] linear, 8 KB
  int tid  = threadIdx.x;
  int lane = tid & 63, wid = tid >> 6;
  int wr = wid >> 1, wc = wid & 1;
  int row0 = blockIdx.y * 128, col0 = blockIdx.x * 128;

  f32x4 acc[4][4] = {};

  // staging geometry: chunk c = wid*2+s covers shorts [c*512, c*512+512)
  // lane covers 8 shorts at c*512 + lane*8  ->  row = c*16 + lane/4, k = (lane&3)*8
  int srow[2];
  int skk = (lane & 3) * 8;
  #pragma unroll
  for (int s = 0; s < 2; s++) {
    int c = wid*2 + s;
    srow[s] = c*16 + (lane >> 2);
  }

  for (int k0 = 0; k0 < KD; k0 += 32) {
    #pragma unroll
    for (int s = 0; s < 2; s++) {
      int c = wid*2 + s;
      ASYNC16(A  + (size_t)(row0 + srow[s])*KD + k0 + skk, &As[c*512]);
      ASYNC16(Wb + (size_t)(col0 + srow[s])*KD + k0 + skk, &Bs[c*512]);
    }
    __syncthreads();

    bf16x8 af[4], bfr[4];
    #pragma unroll
    for (int m = 0; m < 4; m++)
      af[m] = *reinterpret_cast<const bf16x8*>(
          &As[(wr*64 + m*16 + (lane & 15))*32 + ((lane >> 4) * 8)]);
    #pragma unroll
    for (int n = 0; n < 4; n++)
      bfr[n] = *reinterpret_cast<const bf16x8*>(
          &Bs[(wc*64 + n*16 + (lane & 15))*32 + ((lane >> 4) * 8)]);
    #pragma unroll
    for (int m = 0; m < 4; m++)
      #pragma unroll
      for (int n = 0; n < 4; n++)
        acc[m][n] = __builtin_amdgcn_mfma_f32_16x16x32_bf16(af[m], bfr[n], acc[m][n], 0, 0, 0);
    __syncthreads();
  }

  // epilogue: D[row][col], col = lane&15, row = (lane>>4)*4 + reg
  int crow = row0 + wr*64 + ((lane >> 4) * 4);
  int ccol = col0 + wc*64 + (lane & 15);
  #pragma unroll
  for (int m = 0; m < 4; m++) {
    #pragma unroll
    for (int i = 0; i < 4; i++) {
      int r = crow + m*16 + i;
      if constexpr (EPI == 0) {
        int b_ = r / NTOK, nn = r % NTOK;
        const size_t QKVSTRIDE = (size_t)BWIN*NHEAD*NTOK*HDHEAD;
        #pragma unroll
        for (int n = 0; n < 4; n++) {
          int c = ccol + n*16;
          float val = acc[m][n][i] + bias[c];
          int which = c / CDIM, rem = c - which*CDIM;
          int hh = rem >> 5, dd = rem & 31;
          if (which == 0) val *= ATTSCALE;
          outb[(size_t)which*QKVSTRIDE + (((size_t)b_*NHEAD+hh)*NTOK+nn)*HDHEAD + dd]
              = __float2bfloat16(val);
        }
      } else if constexpr (EPI == 1) {
        int b_ = r / NTOK, nn = r % NTOK;
        int b = b_ >> 4, wi = b_ & 15, wh = wi >> 2, ww = wi & 3;
        int ii = nn / WSZ, jj = nn % WSZ;
        int hh = (wh*WSZ + ii + SSZ) % HDIM;
        int wcc = (ww*WSZ + jj + SSZ) % WDIM;
        size_t rr = ((size_t)b*LDIM + hh*WDIM + wcc) * CDIM;
        #pragma unroll
        for (int n = 0; n < 4; n++) {
          int c = ccol + n*16;
          outf[rr+c] = aux[rr+c] + acc[m][n][i] + bias[c];
        }
      } else if constexpr (EPI == 2) {
        #pragma unroll
        for (int n = 0; n < 4; n++) {
          int c = ccol + n*16;
          float val = acc[m][n][i] + bias[c];
          val = 0.5f * val * (1.0f + erff(val * 0.70710678118654752f));
          outb[(size_t)r*HIDDIM + c] = __float2bfloat16(val);
        }
      } else {
        #pragma unroll
        for (int n = 0; n < 4; n++) {
          int c = ccol + n*16;
          outf[(size_t)r*CDIM + c] = acc[m][n][i] + bias[c] + aux[(size_t)r*CDIM + c];
        }
      }
    }
  }
}

// ---------------- fused window attention: one block per (window, head) ----------------
__global__ __launch_bounds__(256) void k_attn(const bf16* __restrict__ q,
    const bf16* __restrict__ k, const bf16* __restrict__ v,
    const float* __restrict__ rt, bf16* __restrict__ out)
{
  int blk = blockIdx.x;               // b_*NHEAD + head
  int b_ = blk / NHEAD, head = blk % NHEAD;
  __shared__ float Ks[NTOK][HDHEAD];
  __shared__ float Vs[NTOK][HDHEAD];
  __shared__ float tabH[729];
  __shared__ float tabR[729];
  __shared__ int   regv[NTOK];
  int tid = threadIdx.x;

  const bf16* kp = k + (size_t)blk*NTOK*HDHEAD;
  const bf16* vp = v + (size_t)blk*NTOK*HDHEAD;
  for (int e = tid; e < NTOK*HDHEAD; e += 256) {
    Ks[e>>5][e&31] = __bfloat162float(kp[e]);
    Vs[e>>5][e&31] = __bfloat162float(vp[e]);
  }
  for (int e = tid; e < 729; e += 256) {
    tabH[e] = rt[e*2*NHEAD + head];
    tabR[e] = rt[e*2*NHEAD + NHEAD + head];
  }
  {
    int wi = b_ & 15, wh = wi >> 2, ww = wi & 3;
    for (int e = tid; e < NTOK; e += 256) {
      int i = e / WSZ, j = e % WSZ;
      int ha = wh*WSZ + i, wa = ww*WSZ + j;
      int rh = ha < (HDIM-WSZ) ? 0 : (ha < (HDIM-SSZ) ? 1 : 2);
      int rw = wa < (WDIM-WSZ) ? 0 : (wa < (WDIM-SSZ) ? 1 : 2);
      regv[e] = rh*3 + rw;
    }
  }
  __syncthreads();
  if (tid >= NTOK) return;
  int n = tid;

  float qr[32];
  const bf16* qp = q + ((size_t)blk*NTOK + n)*HDHEAD;
  #pragma unroll
  for (int d = 0; d < 32; d++) qr[d] = __bfloat162float(qp[d]);
  int ni = n / WSZ, nj = n % WSZ;
  int myreg = regv[n];

  float mmax = -1e30f, lsum = 0.f;
  for (int m = 0; m < NTOK; m++) {
    float s = 0.f;
    #pragma unroll
    for (int d4 = 0; d4 < 8; d4++) {
      float4 kv = ((const float4*)Ks[m])[d4];
      s += qr[d4*4+0]*kv.x + qr[d4*4+1]*kv.y + qr[d4*4+2]*kv.z + qr[d4*4+3]*kv.w;
    }
    int dh = ni - m/WSZ + 13, dw = nj - m%WSZ + 13;
    s += tabH[dh*27 + dw];
    if (regv[m] != myreg) s -= 100.f;
    if (s > mmax) { lsum *= __expf(mmax - s); mmax = s; }
    lsum += __expf(s - mmax);
  }
  float inv = 1.f / lsum;

  float accd[32] = {};
  for (int m = 0; m < NTOK; m++) {
    float s = 0.f;
    #pragma unroll
    for (int d4 = 0; d4 < 8; d4++) {
      float4 kv = ((const float4*)Ks[m])[d4];
      s += qr[d4*4+0]*kv.x + qr[d4*4+1]*kv.y + qr[d4*4+2]*kv.z + qr[d4*4+3]*kv.w;
    }
    int dh = ni - m/WSZ + 13, dw = nj - m%WSZ + 13;
    int idx = dh*27 + dw;
    s += tabH[idx];
    if (regv[m] != myreg) s -= 100.f;
    float p = __expf(s - mmax) * tabR[idx] * inv;
    #pragma unroll
    for (int d4 = 0; d4 < 8; d4++) {
      float4 vv = ((const float4*)Vs[m])[d4];
      accd[d4*4+0] += p*vv.x; accd[d4*4+1] += p*vv.y;
      accd[d4*4+2] += p*vv.z; accd[d4*4+3] += p*vv.w;
    }
  }

  bf16* op = out + ((size_t)b_*NTOK + n)*CDIM + head*HDHEAD;
  #pragma unroll
  for (int d = 0; d < 32; d++) op[d] = __float2bfloat16(accd[d]);
}

// ---------------- launch ----------------
extern "C" void kernel_launch(void* const* d_in, const int* in_sizes, int n_in,
                              void* d_out, int out_size, void* d_ws, size_t ws_size,
                              hipStream_t stream)
{
  const float* x      = (const float*)d_in[0];
  const float* n1w    = (const float*)d_in[1];
  const float* n1b    = (const float*)d_in[2];
  const float* qkv_w  = (const float*)d_in[3];
  const float* qkv_b  = (const float*)d_in[4];
  const float* proj_w = (const float*)d_in[5];
  const float* proj_b = (const float*)d_in[6];
  const float* rt     = (const float*)d_in[7];
  const float* n2w    = (const float*)d_in[8];
  const float* n2b    = (const float*)d_in[9];
  const float* fc1_w  = (const float*)d_in[10];
  const float* fc1_b  = (const float*)d_in[11];
  const float* fc2_w  = (const float*)d_in[12];
  const float* fc2_b  = (const float*)d_in[13];

  char* ws = (char*)d_ws;
  const size_t SZ_BF = (size_t)MROWS * CDIM * 2;   // 77,070,336 B
  // arena (total exactly 8*SZ_BF, the round-1-proven footprint):
  //  R0 [0,1SZ):    xw -> attnout -> (after proj) wf1,wf2
  //  R1 [1SZ,4SZ):  qkv -> x2 (f32, [1SZ,3SZ)) + hln ([3SZ,4SZ))
  //  R2 [4SZ,8SZ):  wq,wp (head) -> hid (overwrites dead wq/wp at fc1)
  bf16*  xw      = (bf16*)ws;
  bf16*  attnout = (bf16*)ws;
  bf16*  qkv     = (bf16*)(ws + SZ_BF);
  float* x2      = (float*)(ws + SZ_BF);
  bf16*  hln     = (bf16*)(ws + 3*SZ_BF);
  bf16*  hid     = (bf16*)(ws + 4*SZ_BF);
  const int NQKVW = 3*CDIM*CDIM;      // 442368
  const int NPROJW = CDIM*CDIM;       // 147456
  const int NFCW  = HIDDIM*CDIM;      // 589824
  bf16* wq  = (bf16*)(ws + 4*SZ_BF);  // lives in R2 until fc1 clobbers it
  bf16* wp  = wq + NQKVW;
  bf16* wf1 = (bf16*)ws;              // converted into R0 after proj GEMM
  bf16* wf2 = wf1 + NFCW;
  const size_t QKVSTRIDE = (size_t)BWIN*NHEAD*NTOK*HDHEAD;

  // phase A: qkv/proj weights into R2 head
  k_cvt<<<(NQKVW+255)/256, 256, 0, stream>>>(qkv_w, wq, NQKVW);
  k_cvt<<<(NPROJW+255)/256, 256, 0, stream>>>(proj_w, wp, NPROJW);

  k_ln<true><<<MROWS, 128, 0, stream>>>(x, n1w, n1b, xw);
  k_mgemm<CDIM, 0><<<dim3((3*CDIM)/128, MROWS/128), 256, 0, stream>>>(
      xw, wq, qkv_b, nullptr, nullptr, qkv);
  k_attn<<<BWIN*NHEAD, 256, 0, stream>>>(
      qkv, qkv + QKVSTRIDE, qkv + 2*QKVSTRIDE, rt, attnout);
  k_mgemm<CDIM, 1><<<dim3(CDIM/128, MROWS/128), 256, 0, stream>>>(
      attnout, wp, proj_b, x, x2, nullptr);

  // phase B: attnout dead -> fc weights into R0
  k_cvt<<<(NFCW+255)/256, 256, 0, stream>>>(fc1_w, wf1, NFCW);
  k_cvt<<<(NFCW+255)/256, 256, 0, stream>>>(fc2_w, wf2, NFCW);

  k_ln<false><<<MROWS, 128, 0, stream>>>(x2, n2w, n2b, hln);
  k_mgemm<CDIM, 2><<<dim3(HIDDIM/128, MROWS/128), 256, 0, stream>>>(
      hln, wf1, fc1_b, nullptr, nullptr, hid);
  k_mgemm<HIDDIM, 3><<<dim3(CDIM/128, MROWS/128), 256, 0, stream>>>(
      hid, wf2, fc2_b, x2, (float*)d_out, nullptr);
}

// Round 5
// 1194.182 us; speedup vs baseline: 6.6597x; 1.8546x over previous
//
#include <hip/hip_runtime.h>
#include <hip/hip_bf16.h>
#include <math.h>

// ---------------- problem constants ----------------
#define BDIM 32
#define HDIM 56
#define WDIM 56
#define CDIM 384
#define NHEAD 12
#define WSZ 14
#define SSZ 7
#define LDIM (HDIM*WDIM)        // 3136
#define NTOK (WSZ*WSZ)          // 196
#define HDHEAD (CDIM/NHEAD)     // 32
#define HIDDIM (4*CDIM)         // 1536
#define NWIN 16
#define BWIN (BDIM*NWIN)        // 512
#define MROWS (BDIM*LDIM)       // 100352 == BWIN*NTOK
#define EPSLN 1e-5f
#define ATTSCALE 0.17677669529663687f   // 32^-0.5

typedef __hip_bfloat16 bf16;
typedef __attribute__((ext_vector_type(8))) short bf16x8;   // 8 bf16 = 4 VGPRs
typedef __attribute__((ext_vector_type(4))) float f32x4;

// async global->LDS, 16B per lane, wave-uniform LDS base
#define ASYNC16(gp, lp) __builtin_amdgcn_global_load_lds( \
    (__attribute__((address_space(1))) void*)(gp),        \
    (__attribute__((address_space(3))) void*)(lp), 16, 0, 0)

// float -> bf16 bit pattern as short (type-consistent with short LDS arrays)
static __device__ __forceinline__ short f2bfs(float x) {
  union { bf16 h; short s; } u; u.h = __float2bfloat16(x); return u.s;
}

// ---------------- fp32 -> bf16 weight convert ----------------
__global__ __launch_bounds__(256) void k_cvt(const float* __restrict__ in,
                                             bf16* __restrict__ out, int n)
{
  int i = blockIdx.x * 256 + threadIdx.x;
  if (i < n) out[i] = __float2bfloat16(in[i]);
}

// ---------------- LN (+optional shift-roll + window partition) ----------------
template<bool WIN>
__global__ __launch_bounds__(128) void k_ln(const float* __restrict__ xin,
    const float* __restrict__ gw, const float* __restrict__ gb,
    bf16* __restrict__ out)
{
  int r = blockIdx.x;
  int t = threadIdx.x;
  const float* xp = xin + (size_t)r * CDIM;
  float v0 = xp[t], v1 = xp[t+128], v2 = xp[t+256];
  float s  = v0+v1+v2;
  float ss = v0*v0 + v1*v1 + v2*v2;
  #pragma unroll
  for (int o = 32; o > 0; o >>= 1) { s += __shfl_down(s, o); ss += __shfl_down(ss, o); }
  __shared__ float red[4];
  if ((t & 63) == 0) { red[(t>>6)*2] = s; red[(t>>6)*2+1] = ss; }
  __syncthreads();
  float mean = (red[0]+red[2]) * (1.0f/CDIM);
  float var  = (red[1]+red[3]) * (1.0f/CDIM) - mean*mean;
  float rstd = rsqrtf(var + EPSLN);

  size_t orow;
  if (WIN) {
    int b = r / LDIM, l = r % LDIM;
    int h = l / WDIM, w = l % WDIM;
    int h2 = (h + HDIM - SSZ) % HDIM, w2 = (w + WDIM - SSZ) % WDIM;
    int wh = h2 / WSZ, ii = h2 % WSZ, ww = w2 / WSZ, jj = w2 % WSZ;
    int b_ = b*NWIN + wh*4 + ww;
    int n  = ii*WSZ + jj;
    orow = ((size_t)b_*NTOK + n) * CDIM;
  } else {
    orow = (size_t)r * CDIM;
  }
  out[orow+t]     = __float2bfloat16((v0-mean)*rstd*gw[t]     + gb[t]);
  out[orow+t+128] = __float2bfloat16((v1-mean)*rstd*gw[t+128] + gb[t+128]);
  out[orow+t+256] = __float2bfloat16((v2-mean)*rstd*gw[t+256] + gb[t+256]);
}

// ---------------- MFMA GEMM: C = A(bf16,MxK) @ Wb(bf16,NCxK)^T ----------------
template<int KD, int EPI>
__global__ __launch_bounds__(256) void k_mgemm(
    const bf16* __restrict__ A, const bf16* __restrict__ Wb,
    const float* __restrict__ bias, const float* __restrict__ aux,
    float* __restrict__ outf, bf16* __restrict__ outb)
{
  __shared__ short As[128*32];   // [row][k] linear, 8 KB
  __shared__ short Bs[128*32];   // [col][k] linear, 8 KB
  int tid  = threadIdx.x;
  int lane = tid & 63, wid = tid >> 6;
  int wr = wid >> 1, wc = wid & 1;
  int row0 = blockIdx.y * 128, col0 = blockIdx.x * 128;

  f32x4 acc[4][4] = {};

  int srow[2];
  int skk = (lane & 3) * 8;
  #pragma unroll
  for (int s = 0; s < 2; s++) {
    int c = wid*2 + s;
    srow[s] = c*16 + (lane >> 2);
  }

  for (int k0 = 0; k0 < KD; k0 += 32) {
    #pragma unroll
    for (int s = 0; s < 2; s++) {
      int c = wid*2 + s;
      ASYNC16(A  + (size_t)(row0 + srow[s])*KD + k0 + skk, &As[c*512]);
      ASYNC16(Wb + (size_t)(col0 + srow[s])*KD + k0 + skk, &Bs[c*512]);
    }
    __syncthreads();

    bf16x8 af[4], bfr[4];
    #pragma unroll
    for (int m = 0; m < 4; m++)
      af[m] = *reinterpret_cast<const bf16x8*>(
          &As[(wr*64 + m*16 + (lane & 15))*32 + ((lane >> 4) * 8)]);
    #pragma unroll
    for (int n = 0; n < 4; n++)
      bfr[n] = *reinterpret_cast<const bf16x8*>(
          &Bs[(wc*64 + n*16 + (lane & 15))*32 + ((lane >> 4) * 8)]);
    #pragma unroll
    for (int m = 0; m < 4; m++)
      #pragma unroll
      for (int n = 0; n < 4; n++)
        acc[m][n] = __builtin_amdgcn_mfma_f32_16x16x32_bf16(af[m], bfr[n], acc[m][n], 0, 0, 0);
    __syncthreads();
  }

  int crow = row0 + wr*64 + ((lane >> 4) * 4);
  int ccol = col0 + wc*64 + (lane & 15);
  #pragma unroll
  for (int m = 0; m < 4; m++) {
    #pragma unroll
    for (int i = 0; i < 4; i++) {
      int r = crow + m*16 + i;
      if constexpr (EPI == 0) {
        int b_ = r / NTOK, nn = r % NTOK;
        const size_t QKVSTRIDE = (size_t)BWIN*NHEAD*NTOK*HDHEAD;
        #pragma unroll
        for (int n = 0; n < 4; n++) {
          int c = ccol + n*16;
          float val = acc[m][n][i] + bias[c];
          int which = c / CDIM, rem = c - which*CDIM;
          int hh = rem >> 5, dd = rem & 31;
          if (which == 0) val *= ATTSCALE;
          outb[(size_t)which*QKVSTRIDE + (((size_t)b_*NHEAD+hh)*NTOK+nn)*HDHEAD + dd]
              = __float2bfloat16(val);
        }
      } else if constexpr (EPI == 1) {
        int b_ = r / NTOK, nn = r % NTOK;
        int b = b_ >> 4, wi = b_ & 15, wh = wi >> 2, ww = wi & 3;
        int ii = nn / WSZ, jj = nn % WSZ;
        int hh = (wh*WSZ + ii + SSZ) % HDIM;
        int wcc = (ww*WSZ + jj + SSZ) % WDIM;
        size_t rr = ((size_t)b*LDIM + hh*WDIM + wcc) * CDIM;
        #pragma unroll
        for (int n = 0; n < 4; n++) {
          int c = ccol + n*16;
          outf[rr+c] = aux[rr+c] + acc[m][n][i] + bias[c];
        }
      } else if constexpr (EPI == 2) {
        #pragma unroll
        for (int n = 0; n < 4; n++) {
          int c = ccol + n*16;
          float val = acc[m][n][i] + bias[c];
          val = 0.5f * val * (1.0f + erff(val * 0.70710678118654752f));
          outb[(size_t)r*HIDDIM + c] = __float2bfloat16(val);
        }
      } else {
        #pragma unroll
        for (int n = 0; n < 4; n++) {
          int c = ccol + n*16;
          outf[(size_t)r*CDIM + c] = acc[m][n][i] + bias[c] + aux[(size_t)r*CDIM + c];
        }
      }
    }
  }
}

// ---------------- MFMA fused window attention (barrier-hardened) ----------------
// One block (4 waves) per (window, head). Uniform loop over 16 strip-slots
// (strips 13..15 dummy compute, writes guarded). __syncthreads between P-write
// and PV-read phases forces full lgkmcnt drain regardless of alias analysis.
__global__ __launch_bounds__(256) void k_attn_mfma(const bf16* __restrict__ q,
    const bf16* __restrict__ k, const bf16* __restrict__ v,
    const float* __restrict__ rt, bf16* __restrict__ out)
{
  __shared__ short  Ks[208*32];     // [m][k], rows 196..207 zero
  __shared__ short  Vt[32*224];     // [d][m], cols 196..223 zero
  __shared__ short  Ps[4][16*224];  // per-wave P strip [row][m]
  __shared__ float2 tab2[729];      // {bias, rscale} per rel-idx for this head
  __shared__ int    regv[208];

  int blk = blockIdx.x;
  int b_ = blk / NHEAD, head = blk % NHEAD;
  int tid = threadIdx.x, lane = tid & 63, wid = tid >> 6;
  int c15 = lane & 15, h4 = lane >> 4;

  // ---- staging ----
  const bf16* kp = k + (size_t)blk*NTOK*HDHEAD;
  const bf16* vp = v + (size_t)blk*NTOK*HDHEAD;
  for (int c = tid; c < 784; c += 256) {          // 196 rows x 4 chunks of 8
    int m = c >> 2, k8 = (c & 3) * 8;
    *(bf16x8*)&Ks[m*32 + k8] = *(const bf16x8*)(kp + m*32 + k8);
    bf16x8 vv = *(const bf16x8*)(vp + m*32 + k8);
    #pragma unroll
    for (int j = 0; j < 8; j++) Vt[(k8+j)*224 + m] = vv[j];
  }
  for (int e = tid; e < 12*32; e += 256) Ks[196*32 + e] = 0;
  for (int e = tid; e < 32*28; e += 256) Vt[(e/28)*224 + 196 + (e%28)] = 0;
  for (int e = tid; e < 729; e += 256)
    tab2[e] = make_float2(rt[e*2*NHEAD + head], rt[e*2*NHEAD + NHEAD + head]);
  {
    int wi = b_ & 15, wh = wi >> 2, ww = wi & 3;
    for (int e = tid; e < 208; e += 256) {
      int rv = 0;
      if (e < NTOK) {
        int i = e / WSZ, j = e % WSZ;
        int ha = wh*WSZ + i, wa = ww*WSZ + j;
        int rh = ha < (HDIM-WSZ) ? 0 : (ha < (HDIM-SSZ) ? 1 : 2);
        int rw = wa < (WDIM-WSZ) ? 0 : (wa < (WDIM-SSZ) ? 1 : 2);
        rv = rh*3 + rw;
      }
      regv[e] = rv;
    }
  }
  __syncthreads();

  // per-lane m-column constants (m = t*16 + c15)
  int   moff[13], mreg[13];
  float mpad[13];
  #pragma unroll
  for (int t = 0; t < 13; t++) {
    int m  = t*16 + c15;
    int mm = min(m, NTOK-1);
    moff[t] = (mm/WSZ)*27 + (mm%WSZ);
    mreg[t] = regv[mm];
    mpad[t] = (m >= NTOK) ? -1e30f : 0.f;
  }

  short* myP = &Ps[wid][0];
  // zero pad cols 208..223 once (never overwritten: softmax writes cols 0..207)
  #pragma unroll
  for (int i = 0; i < 4; i++) myP[(h4*4+i)*224 + 208 + c15] = 0;

  bf16* op = out + (size_t)b_*NTOK*CDIM + head*HDHEAD;

  for (int t4 = 0; t4 < 4; t4++) {
    int s = t4*4 + wid;                 // 0..15; 13..15 dummy (writes guarded)
    // Q A-frag straight from global (rows clamped; garbage rows never written)
    int qrow = min(s*16 + c15, NTOK-1);
    bf16x8 qf = *(const bf16x8*)(q + ((size_t)blk*NTOK + qrow)*HDHEAD + h4*8);

    f32x4 sc[13];
    #pragma unroll
    for (int t = 0; t < 13; t++) {
      bf16x8 kf = *(const bf16x8*)&Ks[(t*16 + c15)*32 + h4*8];
      sc[t] = __builtin_amdgcn_mfma_f32_16x16x32_bf16(qf, kf, (f32x4){0.f,0.f,0.f,0.f}, 0, 0, 0);
    }

    #pragma unroll
    for (int i = 0; i < 4; i++) {
      int n  = s*16 + h4*4 + i;
      int nc = min(n, NTOK-1);
      int nbase = ((nc/WSZ) + 13)*27 + (nc%WSZ) + 13;
      int nreg  = regv[nc];
      float rr[13];
      float mx = -1e30f;
      #pragma unroll
      for (int t = 0; t < 13; t++) {
        float2 hr = tab2[nbase - moff[t]];
        float sv = sc[t][i] + hr.x + ((mreg[t] != nreg) ? -100.f : 0.f) + mpad[t];
        rr[t] = hr.y;
        sc[t][i] = sv;
        mx = fmaxf(mx, sv);
      }
      #pragma unroll
      for (int o = 1; o < 16; o <<= 1) mx = fmaxf(mx, __shfl_xor(mx, o));
      float sum = 0.f;
      #pragma unroll
      for (int t = 0; t < 13; t++) {
        float e = __expf(sc[t][i] - mx);
        sc[t][i] = e; sum += e;
      }
      #pragma unroll
      for (int o = 1; o < 16; o <<= 1) sum += __shfl_xor(sum, o);
      float inv = 1.f / sum;
      int prow = h4*4 + i;
      #pragma unroll
      for (int t = 0; t < 13; t++)
        myP[prow*224 + t*16 + c15] = f2bfs(sc[t][i] * inv * rr[t]);   // short store
    }

    __syncthreads();   // drain P ds_writes before PV ds_reads (all waves uniform)

    // PV: O[16 x 32] = P[16 x 224] @ Vt^T
    f32x4 o0 = {0.f,0.f,0.f,0.f}, o1 = {0.f,0.f,0.f,0.f};
    #pragma unroll
    for (int t7 = 0; t7 < 7; t7++) {
      bf16x8 pf = *(const bf16x8*)&myP[c15*224 + t7*32 + h4*8];
      bf16x8 v0 = *(const bf16x8*)&Vt[c15*224 + t7*32 + h4*8];
      bf16x8 v1 = *(const bf16x8*)&Vt[(16 + c15)*224 + t7*32 + h4*8];
      o0 = __builtin_amdgcn_mfma_f32_16x16x32_bf16(pf, v0, o0, 0, 0, 0);
      o1 = __builtin_amdgcn_mfma_f32_16x16x32_bf16(pf, v1, o1, 0, 0, 0);
    }

    #pragma unroll
    for (int i = 0; i < 4; i++) {
      int n = s*16 + h4*4 + i;
      if (n < NTOK) {
        op[(size_t)n*CDIM + c15]      = __float2bfloat16(o0[i]);
        op[(size_t)n*CDIM + 16 + c15] = __float2bfloat16(o1[i]);
      }
    }

    __syncthreads();   // PV reads done before next strip's P writes
  }
}

// ---------------- launch ----------------
extern "C" void kernel_launch(void* const* d_in, const int* in_sizes, int n_in,
                              void* d_out, int out_size, void* d_ws, size_t ws_size,
                              hipStream_t stream)
{
  const float* x      = (const float*)d_in[0];
  const float* n1w    = (const float*)d_in[1];
  const float* n1b    = (const float*)d_in[2];
  const float* qkv_w  = (const float*)d_in[3];
  const float* qkv_b  = (const float*)d_in[4];
  const float* proj_w = (const float*)d_in[5];
  const float* proj_b = (const float*)d_in[6];
  const float* rt     = (const float*)d_in[7];
  const float* n2w    = (const float*)d_in[8];
  const float* n2b    = (const float*)d_in[9];
  const float* fc1_w  = (const float*)d_in[10];
  const float* fc1_b  = (const float*)d_in[11];
  const float* fc2_w  = (const float*)d_in[12];
  const float* fc2_b  = (const float*)d_in[13];

  char* ws = (char*)d_ws;
  const size_t SZ_BF = (size_t)MROWS * CDIM * 2;   // 77,070,336 B
  // arena (total exactly 8*SZ_BF, the round-1-proven footprint):
  //  R0 [0,1SZ):    xw -> attnout -> (after proj) wf1,wf2
  //  R1 [1SZ,4SZ):  qkv -> x2 (f32, [1SZ,3SZ)) + hln ([3SZ,4SZ))
  //  R2 [4SZ,8SZ):  wq,wp (head) -> hid (overwrites dead wq/wp at fc1)
  bf16*  xw      = (bf16*)ws;
  bf16*  attnout = (bf16*)ws;
  bf16*  qkv     = (bf16*)(ws + SZ_BF);
  float* x2      = (float*)(ws + SZ_BF);
  bf16*  hln     = (bf16*)(ws + 3*SZ_BF);
  bf16*  hid     = (bf16*)(ws + 4*SZ_BF);
  const int NQKVW = 3*CDIM*CDIM;      // 442368
  const int NPROJW = CDIM*CDIM;       // 147456
  const int NFCW  = HIDDIM*CDIM;      // 589824
  bf16* wq  = (bf16*)(ws + 4*SZ_BF);  // lives in R2 until fc1 clobbers it
  bf16* wp  = wq + NQKVW;
  bf16* wf1 = (bf16*)ws;              // converted into R0 after proj GEMM
  bf16* wf2 = wf1 + NFCW;
  const size_t QKVSTRIDE = (size_t)BWIN*NHEAD*NTOK*HDHEAD;

  k_cvt<<<(NQKVW+255)/256, 256, 0, stream>>>(qkv_w, wq, NQKVW);
  k_cvt<<<(NPROJW+255)/256, 256, 0, stream>>>(proj_w, wp, NPROJW);

  k_ln<true><<<MROWS, 128, 0, stream>>>(x, n1w, n1b, xw);
  k_mgemm<CDIM, 0><<<dim3((3*CDIM)/128, MROWS/128), 256, 0, stream>>>(
      xw, wq, qkv_b, nullptr, nullptr, qkv);
  k_attn_mfma<<<BWIN*NHEAD, 256, 0, stream>>>(
      qkv, qkv + QKVSTRIDE, qkv + 2*QKVSTRIDE, rt, attnout);
  k_mgemm<CDIM, 1><<<dim3(CDIM/128, MROWS/128), 256, 0, stream>>>(
      attnout, wp, proj_b, x, x2, nullptr);

  k_cvt<<<(NFCW+255)/256, 256, 0, stream>>>(fc1_w, wf1, NFCW);
  k_cvt<<<(NFCW+255)/256, 256, 0, stream>>>(fc2_w, wf2, NFCW);

  k_ln<false><<<MROWS, 128, 0, stream>>>(x2, n2w, n2b, hln);
  k_mgemm<CDIM, 2><<<dim3(HIDDIM/128, MROWS/128), 256, 0, stream>>>(
      hln, wf1, fc1_b, nullptr, nullptr, hid);
  k_mgemm<HIDDIM, 3><<<dim3(CDIM/128, MROWS/128), 256, 0, stream>>>(
      hid, wf2, fc2_b, x2, (float*)d_out, nullptr);
}

// Round 6
// 1153.546 us; speedup vs baseline: 6.8943x; 1.0352x over previous
//
#include <hip/hip_runtime.h>
#include <hip/hip_bf16.h>
#include <math.h>

// ---------------- problem constants ----------------
#define BDIM 32
#define HDIM 56
#define WDIM 56
#define CDIM 384
#define NHEAD 12
#define WSZ 14
#define SSZ 7
#define LDIM (HDIM*WDIM)        // 3136
#define NTOK (WSZ*WSZ)          // 196
#define HDHEAD (CDIM/NHEAD)     // 32
#define HIDDIM (4*CDIM)         // 1536
#define NWIN 16
#define BWIN (BDIM*NWIN)        // 512
#define MROWS (BDIM*LDIM)       // 100352 == BWIN*NTOK
#define EPSLN 1e-5f
#define ATTSCALE 0.17677669529663687f   // 32^-0.5

// padded LDS strides (shorts): word-stride ≡ 20 mod 32 -> 2 lanes/bank (free)
#define KROW 40
#define VROW 232
#define PROW 232

typedef __hip_bfloat16 bf16;
typedef __attribute__((ext_vector_type(8))) short bf16x8;   // 8 bf16 = 4 VGPRs
typedef __attribute__((ext_vector_type(4))) float f32x4;

// async global->LDS, 16B per lane, wave-uniform LDS base
#define ASYNC16(gp, lp) __builtin_amdgcn_global_load_lds( \
    (__attribute__((address_space(1))) void*)(gp),        \
    (__attribute__((address_space(3))) void*)(lp), 16, 0, 0)

// float -> bf16 bit pattern as short (type-consistent with short LDS arrays)
static __device__ __forceinline__ short f2bfs(float x) {
  union { bf16 h; short s; } u; u.h = __float2bfloat16(x); return u.s;
}
static __device__ __forceinline__ float tof(float x) { return x; }
static __device__ __forceinline__ float tof(bf16 x)  { return __bfloat162float(x); }

// ---------------- fp32 -> bf16 weight convert ----------------
__global__ __launch_bounds__(256) void k_cvt(const float* __restrict__ in,
                                             bf16* __restrict__ out, int n)
{
  int i = blockIdx.x * 256 + threadIdx.x;
  if (i < n) out[i] = __float2bfloat16(in[i]);
}

// ---------------- LN (+optional shift-roll + window partition) ----------------
template<bool WIN, typename TIN>
__global__ __launch_bounds__(128) void k_ln(const TIN* __restrict__ xin,
    const float* __restrict__ gw, const float* __restrict__ gb,
    bf16* __restrict__ out)
{
  int r = blockIdx.x;
  int t = threadIdx.x;
  const TIN* xp = xin + (size_t)r * CDIM;
  float v0 = tof(xp[t]), v1 = tof(xp[t+128]), v2 = tof(xp[t+256]);
  float s  = v0+v1+v2;
  float ss = v0*v0 + v1*v1 + v2*v2;
  #pragma unroll
  for (int o = 32; o > 0; o >>= 1) { s += __shfl_down(s, o); ss += __shfl_down(ss, o); }
  __shared__ float red[4];
  if ((t & 63) == 0) { red[(t>>6)*2] = s; red[(t>>6)*2+1] = ss; }
  __syncthreads();
  float mean = (red[0]+red[2]) * (1.0f/CDIM);
  float var  = (red[1]+red[3]) * (1.0f/CDIM) - mean*mean;
  float rstd = rsqrtf(var + EPSLN);

  size_t orow;
  if (WIN) {
    int b = r / LDIM, l = r % LDIM;
    int h = l / WDIM, w = l % WDIM;
    int h2 = (h + HDIM - SSZ) % HDIM, w2 = (w + WDIM - SSZ) % WDIM;
    int wh = h2 / WSZ, ii = h2 % WSZ, ww = w2 / WSZ, jj = w2 % WSZ;
    int b_ = b*NWIN + wh*4 + ww;
    int n  = ii*WSZ + jj;
    orow = ((size_t)b_*NTOK + n) * CDIM;
  } else {
    orow = (size_t)r * CDIM;
  }
  out[orow+t]     = __float2bfloat16((v0-mean)*rstd*gw[t]     + gb[t]);
  out[orow+t+128] = __float2bfloat16((v1-mean)*rstd*gw[t+128] + gb[t+128]);
  out[orow+t+256] = __float2bfloat16((v2-mean)*rstd*gw[t+256] + gb[t+256]);
}

// ---------------- MFMA GEMM: C = A(bf16,MxK) @ Wb(bf16,NCxK)^T ----------------
// EPI 0: qkv scatter (+SCALE on q)   EPI 1: proj + window-reverse + residual(f32 aux) -> bf16 x2
// EPI 2: fc1 + exact gelu -> bf16    EPI 3: fc2 + bias + residual(bf16 auxb) -> f32
template<int KD, int EPI>
__global__ __launch_bounds__(256) void k_mgemm(
    const bf16* __restrict__ A, const bf16* __restrict__ Wb,
    const float* __restrict__ bias, const float* __restrict__ aux,
    const bf16* __restrict__ auxb,
    float* __restrict__ outf, bf16* __restrict__ outb)
{
  __shared__ short As[128*32];   // [row][k] linear, 8 KB
  __shared__ short Bs[128*32];   // [col][k] linear, 8 KB
  int tid  = threadIdx.x;
  int lane = tid & 63, wid = tid >> 6;
  int wr = wid >> 1, wc = wid & 1;
  int row0 = blockIdx.y * 128, col0 = blockIdx.x * 128;

  f32x4 acc[4][4] = {};

  int srow[2];
  int skk = (lane & 3) * 8;
  #pragma unroll
  for (int s = 0; s < 2; s++) {
    int c = wid*2 + s;
    srow[s] = c*16 + (lane >> 2);
  }

  for (int k0 = 0; k0 < KD; k0 += 32) {
    #pragma unroll
    for (int s = 0; s < 2; s++) {
      int c = wid*2 + s;
      ASYNC16(A  + (size_t)(row0 + srow[s])*KD + k0 + skk, &As[c*512]);
      ASYNC16(Wb + (size_t)(col0 + srow[s])*KD + k0 + skk, &Bs[c*512]);
    }
    __syncthreads();

    bf16x8 af[4], bfr[4];
    #pragma unroll
    for (int m = 0; m < 4; m++)
      af[m] = *reinterpret_cast<const bf16x8*>(
          &As[(wr*64 + m*16 + (lane & 15))*32 + ((lane >> 4) * 8)]);
    #pragma unroll
    for (int n = 0; n < 4; n++)
      bfr[n] = *reinterpret_cast<const bf16x8*>(
          &Bs[(wc*64 + n*16 + (lane & 15))*32 + ((lane >> 4) * 8)]);
    #pragma unroll
    for (int m = 0; m < 4; m++)
      #pragma unroll
      for (int n = 0; n < 4; n++)
        acc[m][n] = __builtin_amdgcn_mfma_f32_16x16x32_bf16(af[m], bfr[n], acc[m][n], 0, 0, 0);
    __syncthreads();
  }

  int crow = row0 + wr*64 + ((lane >> 4) * 4);
  int ccol = col0 + wc*64 + (lane & 15);
  #pragma unroll
  for (int m = 0; m < 4; m++) {
    #pragma unroll
    for (int i = 0; i < 4; i++) {
      int r = crow + m*16 + i;
      if constexpr (EPI == 0) {
        int b_ = r / NTOK, nn = r % NTOK;
        const size_t QKVSTRIDE = (size_t)BWIN*NHEAD*NTOK*HDHEAD;
        #pragma unroll
        for (int n = 0; n < 4; n++) {
          int c = ccol + n*16;
          float val = acc[m][n][i] + bias[c];
          int which = c / CDIM, rem = c - which*CDIM;
          int hh = rem >> 5, dd = rem & 31;
          if (which == 0) val *= ATTSCALE;
          outb[(size_t)which*QKVSTRIDE + (((size_t)b_*NHEAD+hh)*NTOK+nn)*HDHEAD + dd]
              = __float2bfloat16(val);
        }
      } else if constexpr (EPI == 1) {
        int b_ = r / NTOK, nn = r % NTOK;
        int b = b_ >> 4, wi = b_ & 15, wh = wi >> 2, ww = wi & 3;
        int ii = nn / WSZ, jj = nn % WSZ;
        int hh = (wh*WSZ + ii + SSZ) % HDIM;
        int wcc = (ww*WSZ + jj + SSZ) % WDIM;
        size_t rr = ((size_t)b*LDIM + hh*WDIM + wcc) * CDIM;
        #pragma unroll
        for (int n = 0; n < 4; n++) {
          int c = ccol + n*16;
          outb[rr+c] = __float2bfloat16(aux[rr+c] + acc[m][n][i] + bias[c]);
        }
      } else if constexpr (EPI == 2) {
        #pragma unroll
        for (int n = 0; n < 4; n++) {
          int c = ccol + n*16;
          float val = acc[m][n][i] + bias[c];
          val = 0.5f * val * (1.0f + erff(val * 0.70710678118654752f));
          outb[(size_t)r*HIDDIM + c] = __float2bfloat16(val);
        }
      } else {
        #pragma unroll
        for (int n = 0; n < 4; n++) {
          int c = ccol + n*16;
          outf[(size_t)r*CDIM + c] = acc[m][n][i] + bias[c]
              + __bfloat162float(auxb[(size_t)r*CDIM + c]);
        }
      }
    }
  }
}

// ---------------- MFMA fused window attention (barrier-hardened, padded LDS) ----------------
__global__ __launch_bounds__(256) void k_attn_mfma(const bf16* __restrict__ q,
    const bf16* __restrict__ k, const bf16* __restrict__ v,
    const float* __restrict__ rt, bf16* __restrict__ out)
{
  __shared__ short  Ks[208*KROW];   // [m][k], rows 196..207 zero, padded stride
  __shared__ short  Vt[32*VROW];    // [d][m], cols 196..223 zero, padded stride
  __shared__ short  Ps[4][16*PROW]; // per-wave P strip [row][m], padded stride
  __shared__ float2 tab2[729];      // {bias, rscale} per rel-idx for this head
  __shared__ int    regv[208];

  int blk = blockIdx.x;
  int b_ = blk / NHEAD, head = blk % NHEAD;
  int tid = threadIdx.x, lane = tid & 63, wid = tid >> 6;
  int c15 = lane & 15, h4 = lane >> 4;

  // ---- staging ----
  const bf16* kp = k + (size_t)blk*NTOK*HDHEAD;
  const bf16* vp = v + (size_t)blk*NTOK*HDHEAD;
  for (int c = tid; c < 784; c += 256) {          // 196 rows x 4 chunks of 8
    int m = c >> 2, k8 = (c & 3) * 8;
    *(bf16x8*)&Ks[m*KROW + k8] = *(const bf16x8*)(kp + m*32 + k8);
    bf16x8 vv = *(const bf16x8*)(vp + m*32 + k8);
    #pragma unroll
    for (int j = 0; j < 8; j++) Vt[(k8+j)*VROW + m] = vv[j];
  }
  for (int e = tid; e < 12*KROW; e += 256) Ks[196*KROW + e] = 0;
  for (int e = tid; e < 32*28; e += 256) Vt[(e/28)*VROW + 196 + (e%28)] = 0;
  for (int e = tid; e < 729; e += 256)
    tab2[e] = make_float2(rt[e*2*NHEAD + head], rt[e*2*NHEAD + NHEAD + head]);
  {
    int wi = b_ & 15, wh = wi >> 2, ww = wi & 3;
    for (int e = tid; e < 208; e += 256) {
      int rv = 0;
      if (e < NTOK) {
        int i = e / WSZ, j = e % WSZ;
        int ha = wh*WSZ + i, wa = ww*WSZ + j;
        int rh = ha < (HDIM-WSZ) ? 0 : (ha < (HDIM-SSZ) ? 1 : 2);
        int rw = wa < (WDIM-WSZ) ? 0 : (wa < (WDIM-SSZ) ? 1 : 2);
        rv = rh*3 + rw;
      }
      regv[e] = rv;
    }
  }
  __syncthreads();

  // per-lane m-column constants (m = t*16 + c15)
  int   moff[13], mreg[13];
  float mpad[13];
  #pragma unroll
  for (int t = 0; t < 13; t++) {
    int m  = t*16 + c15;
    int mm = min(m, NTOK-1);
    moff[t] = (mm/WSZ)*27 + (mm%WSZ);
    mreg[t] = regv[mm];
    mpad[t] = (m >= NTOK) ? -1e30f : 0.f;
  }

  short* myP = &Ps[wid][0];
  // zero pad cols 208..223 once (never overwritten: softmax writes cols 0..207)
  #pragma unroll
  for (int i = 0; i < 4; i++) myP[(h4*4+i)*PROW + 208 + c15] = 0;

  bf16* op = out + (size_t)b_*NTOK*CDIM + head*HDHEAD;

  for (int t4 = 0; t4 < 4; t4++) {
    int s = t4*4 + wid;                 // 0..15; 13..15 dummy (writes guarded)
    int qrow = min(s*16 + c15, NTOK-1);
    bf16x8 qf = *(const bf16x8*)(q + ((size_t)blk*NTOK + qrow)*HDHEAD + h4*8);

    f32x4 sc[13];
    #pragma unroll
    for (int t = 0; t < 13; t++) {
      bf16x8 kf = *(const bf16x8*)&Ks[(t*16 + c15)*KROW + h4*8];
      sc[t] = __builtin_amdgcn_mfma_f32_16x16x32_bf16(qf, kf, (f32x4){0.f,0.f,0.f,0.f}, 0, 0, 0);
    }

    #pragma unroll
    for (int i = 0; i < 4; i++) {
      int n  = s*16 + h4*4 + i;
      int nc = min(n, NTOK-1);
      int nbase = ((nc/WSZ) + 13)*27 + (nc%WSZ) + 13;
      int nreg  = regv[nc];
      float rr[13];
      float mx = -1e30f;
      #pragma unroll
      for (int t = 0; t < 13; t++) {
        float2 hr = tab2[nbase - moff[t]];
        float sv = sc[t][i] + hr.x + ((mreg[t] != nreg) ? -100.f : 0.f) + mpad[t];
        rr[t] = hr.y;
        sc[t][i] = sv;
        mx = fmaxf(mx, sv);
      }
      #pragma unroll
      for (int o = 1; o < 16; o <<= 1) mx = fmaxf(mx, __shfl_xor(mx, o));
      float sum = 0.f;
      #pragma unroll
      for (int t = 0; t < 13; t++) {
        float e = __expf(sc[t][i] - mx);
        sc[t][i] = e; sum += e;
      }
      #pragma unroll
      for (int o = 1; o < 16; o <<= 1) sum += __shfl_xor(sum, o);
      float inv = 1.f / sum;
      int prow = h4*4 + i;
      #pragma unroll
      for (int t = 0; t < 13; t++)
        myP[prow*PROW + t*16 + c15] = f2bfs(sc[t][i] * inv * rr[t]);   // short store
    }

    __syncthreads();   // drain P ds_writes before PV ds_reads (all waves uniform)

    // PV: O[16 x 32] = P[16 x 224] @ Vt^T
    f32x4 o0 = {0.f,0.f,0.f,0.f}, o1 = {0.f,0.f,0.f,0.f};
    #pragma unroll
    for (int t7 = 0; t7 < 7; t7++) {
      bf16x8 pf = *(const bf16x8*)&myP[c15*PROW + t7*32 + h4*8];
      bf16x8 v0 = *(const bf16x8*)&Vt[c15*VROW + t7*32 + h4*8];
      bf16x8 v1 = *(const bf16x8*)&Vt[(16 + c15)*VROW + t7*32 + h4*8];
      o0 = __builtin_amdgcn_mfma_f32_16x16x32_bf16(pf, v0, o0, 0, 0, 0);
      o1 = __builtin_amdgcn_mfma_f32_16x16x32_bf16(pf, v1, o1, 0, 0, 0);
    }

    #pragma unroll
    for (int i = 0; i < 4; i++) {
      int n = s*16 + h4*4 + i;
      if (n < NTOK) {
        op[(size_t)n*CDIM + c15]      = __float2bfloat16(o0[i]);
        op[(size_t)n*CDIM + 16 + c15] = __float2bfloat16(o1[i]);
      }
    }

    __syncthreads();   // PV reads done before next strip's P writes
  }
}

// ---------------- launch ----------------
extern "C" void kernel_launch(void* const* d_in, const int* in_sizes, int n_in,
                              void* d_out, int out_size, void* d_ws, size_t ws_size,
                              hipStream_t stream)
{
  const float* x      = (const float*)d_in[0];
  const float* n1w    = (const float*)d_in[1];
  const float* n1b    = (const float*)d_in[2];
  const float* qkv_w  = (const float*)d_in[3];
  const float* qkv_b  = (const float*)d_in[4];
  const float* proj_w = (const float*)d_in[5];
  const float* proj_b = (const float*)d_in[6];
  const float* rt     = (const float*)d_in[7];
  const float* n2w    = (const float*)d_in[8];
  const float* n2b    = (const float*)d_in[9];
  const float* fc1_w  = (const float*)d_in[10];
  const float* fc1_b  = (const float*)d_in[11];
  const float* fc2_w  = (const float*)d_in[12];
  const float* fc2_b  = (const float*)d_in[13];

  char* ws = (char*)d_ws;
  const size_t SZ_BF = (size_t)MROWS * CDIM * 2;   // 77,070,336 B
  // arena (total exactly 8*SZ_BF, proven footprint):
  //  R0 [0,1SZ):    xw -> attnout -> (after proj) wf1,wf2
  //  R1 [1SZ,4SZ):  qkv -> x2(bf16,[1SZ,2SZ)) + hln([2SZ,3SZ))
  //  R2 [4SZ,8SZ):  wq,wp (head) -> hid (overwrites dead wq/wp at fc1)
  bf16*  xw      = (bf16*)ws;
  bf16*  attnout = (bf16*)ws;
  bf16*  qkv     = (bf16*)(ws + SZ_BF);
  bf16*  x2b     = (bf16*)(ws + SZ_BF);
  bf16*  hln     = (bf16*)(ws + 2*SZ_BF);
  bf16*  hid     = (bf16*)(ws + 4*SZ_BF);
  const int NQKVW = 3*CDIM*CDIM;      // 442368
  const int NPROJW = CDIM*CDIM;       // 147456
  const int NFCW  = HIDDIM*CDIM;      // 589824
  bf16* wq  = (bf16*)(ws + 4*SZ_BF);  // lives in R2 until fc1 clobbers it
  bf16* wp  = wq + NQKVW;
  bf16* wf1 = (bf16*)ws;              // converted into R0 after proj GEMM
  bf16* wf2 = wf1 + NFCW;
  const size_t QKVSTRIDE = (size_t)BWIN*NHEAD*NTOK*HDHEAD;

  k_cvt<<<(NQKVW+255)/256, 256, 0, stream>>>(qkv_w, wq, NQKVW);
  k_cvt<<<(NPROJW+255)/256, 256, 0, stream>>>(proj_w, wp, NPROJW);

  k_ln<true, float><<<MROWS, 128, 0, stream>>>(x, n1w, n1b, xw);
  k_mgemm<CDIM, 0><<<dim3((3*CDIM)/128, MROWS/128), 256, 0, stream>>>(
      xw, wq, qkv_b, nullptr, nullptr, nullptr, qkv);
  k_attn_mfma<<<BWIN*NHEAD, 256, 0, stream>>>(
      qkv, qkv + QKVSTRIDE, qkv + 2*QKVSTRIDE, rt, attnout);
  k_mgemm<CDIM, 1><<<dim3(CDIM/128, MROWS/128), 256, 0, stream>>>(
      attnout, wp, proj_b, x, nullptr, nullptr, x2b);

  k_cvt<<<(NFCW+255)/256, 256, 0, stream>>>(fc1_w, wf1, NFCW);
  k_cvt<<<(NFCW+255)/256, 256, 0, stream>>>(fc2_w, wf2, NFCW);

  k_ln<false, bf16><<<MROWS, 128, 0, stream>>>(x2b, n2w, n2b, hln);
  k_mgemm<CDIM, 2><<<dim3(HIDDIM/128, MROWS/128), 256, 0, stream>>>(
      hln, wf1, fc1_b, nullptr, nullptr, nullptr, hid);
  k_mgemm<HIDDIM, 3><<<dim3(CDIM/128, MROWS/128), 256, 0, stream>>>(
      hid, wf2, fc2_b, nullptr, x2b, (float*)d_out, nullptr);
}

// Round 7
// 1126.324 us; speedup vs baseline: 7.0609x; 1.0242x over previous
//
#include <hip/hip_runtime.h>
#include <hip/hip_bf16.h>
#include <math.h>

// ---------------- problem constants ----------------
#define BDIM 32
#define HDIM 56
#define WDIM 56
#define CDIM 384
#define NHEAD 12
#define WSZ 14
#define SSZ 7
#define LDIM (HDIM*WDIM)        // 3136
#define NTOK (WSZ*WSZ)          // 196
#define HDHEAD (CDIM/NHEAD)     // 32
#define HIDDIM (4*CDIM)         // 1536
#define NWIN 16
#define BWIN (BDIM*NWIN)        // 512
#define MROWS (BDIM*LDIM)       // 100352 == BWIN*NTOK
#define EPSLN 1e-5f
#define ATTSCALE 0.17677669529663687f   // 32^-0.5

// padded LDS strides (shorts): word-stride ≡ 20 mod 32 -> 2 lanes/bank (free)
#define KROW 40
#define VROW 232
#define PROW 232

typedef __hip_bfloat16 bf16;
typedef __attribute__((ext_vector_type(8))) short bf16x8;   // 8 bf16 = 4 VGPRs
typedef __attribute__((ext_vector_type(4))) short s16x4;    // 4 bf16 = 1 b64 store
typedef __attribute__((ext_vector_type(4))) float f32x4;

// async global->LDS, 16B per lane, wave-uniform LDS base
#define ASYNC16(gp, lp) __builtin_amdgcn_global_load_lds( \
    (__attribute__((address_space(1))) void*)(gp),        \
    (__attribute__((address_space(3))) void*)(lp), 16, 0, 0)

// float -> bf16 bit pattern as short (type-consistent with short LDS arrays)
static __device__ __forceinline__ short f2bfs(float x) {
  union { bf16 h; short s; } u; u.h = __float2bfloat16(x); return u.s;
}
static __device__ __forceinline__ float bfs2f(short s) {
  unsigned int u = ((unsigned int)(unsigned short)s) << 16;
  float f; __builtin_memcpy(&f, &u, 4); return f;
}
static __device__ __forceinline__ float tof(float x) { return x; }
static __device__ __forceinline__ float tof(bf16 x)  { return __bfloat162float(x); }

// ---------------- fp32 -> bf16 weight convert ----------------
__global__ __launch_bounds__(256) void k_cvt(const float* __restrict__ in,
                                             bf16* __restrict__ out, int n)
{
  int i = blockIdx.x * 256 + threadIdx.x;
  if (i < n) out[i] = __float2bfloat16(in[i]);
}

// ---------------- LN (+optional shift-roll + window partition) ----------------
template<bool WIN, typename TIN>
__global__ __launch_bounds__(128) void k_ln(const TIN* __restrict__ xin,
    const float* __restrict__ gw, const float* __restrict__ gb,
    bf16* __restrict__ out)
{
  int r = blockIdx.x;
  int t = threadIdx.x;
  const TIN* xp = xin + (size_t)r * CDIM;
  float v0 = tof(xp[t]), v1 = tof(xp[t+128]), v2 = tof(xp[t+256]);
  float s  = v0+v1+v2;
  float ss = v0*v0 + v1*v1 + v2*v2;
  #pragma unroll
  for (int o = 32; o > 0; o >>= 1) { s += __shfl_down(s, o); ss += __shfl_down(ss, o); }
  __shared__ float red[4];
  if ((t & 63) == 0) { red[(t>>6)*2] = s; red[(t>>6)*2+1] = ss; }
  __syncthreads();
  float mean = (red[0]+red[2]) * (1.0f/CDIM);
  float var  = (red[1]+red[3]) * (1.0f/CDIM) - mean*mean;
  float rstd = rsqrtf(var + EPSLN);

  size_t orow;
  if (WIN) {
    int b = r / LDIM, l = r % LDIM;
    int h = l / WDIM, w = l % WDIM;
    int h2 = (h + HDIM - SSZ) % HDIM, w2 = (w + WDIM - SSZ) % WDIM;
    int wh = h2 / WSZ, ii = h2 % WSZ, ww = w2 / WSZ, jj = w2 % WSZ;
    int b_ = b*NWIN + wh*4 + ww;
    int n  = ii*WSZ + jj;
    orow = ((size_t)b_*NTOK + n) * CDIM;
  } else {
    orow = (size_t)r * CDIM;
  }
  out[orow+t]     = __float2bfloat16((v0-mean)*rstd*gw[t]     + gb[t]);
  out[orow+t+128] = __float2bfloat16((v1-mean)*rstd*gw[t+128] + gb[t+128]);
  out[orow+t+256] = __float2bfloat16((v2-mean)*rstd*gw[t+256] + gb[t+256]);
}

// ---------------- MFMA GEMM: C = A(bf16,MxK) @ Wb(bf16,NCxK)^T ----------------
// Operand-SWAPPED MFMA: acc[n][m] = mfma(W-frag, A-frag) so each lane holds a
// fixed output row and 4 CONSECUTIVE output cols per reg quad -> vector epilogue.
// EPI 0: qkv scatter (+SCALE on q)   EPI 1: proj + window-reverse + residual(f32) -> bf16
// EPI 2: fc1 + exact gelu -> bf16    EPI 3: fc2 + bias + residual(bf16) -> f32
template<int KD, int EPI>
__global__ __launch_bounds__(256) void k_mgemm(
    const bf16* __restrict__ A, const bf16* __restrict__ Wb,
    const float* __restrict__ bias, const float* __restrict__ aux,
    const bf16* __restrict__ auxb,
    float* __restrict__ outf, bf16* __restrict__ outb)
{
  __shared__ short As[128*32];   // [row][k] linear, 8 KB
  __shared__ short Bs[128*32];   // [col][k] linear, 8 KB
  int tid  = threadIdx.x;
  int lane = tid & 63, wid = tid >> 6;
  int c15 = lane & 15, h4 = lane >> 4;
  int wr = wid >> 1, wc = wid & 1;
  int row0 = blockIdx.y * 128, col0 = blockIdx.x * 128;

  f32x4 acc[4][4] = {};          // [n][m]

  int srow[2];
  int skk = (lane & 3) * 8;
  #pragma unroll
  for (int s = 0; s < 2; s++) {
    int c = wid*2 + s;
    srow[s] = c*16 + (lane >> 2);
  }

  for (int k0 = 0; k0 < KD; k0 += 32) {
    #pragma unroll
    for (int s = 0; s < 2; s++) {
      int c = wid*2 + s;
      ASYNC16(A  + (size_t)(row0 + srow[s])*KD + k0 + skk, &As[c*512]);
      ASYNC16(Wb + (size_t)(col0 + srow[s])*KD + k0 + skk, &Bs[c*512]);
    }
    __syncthreads();

    bf16x8 af[4], bfr[4];
    #pragma unroll
    for (int m = 0; m < 4; m++)
      af[m] = *reinterpret_cast<const bf16x8*>(
          &As[(wr*64 + m*16 + c15)*32 + h4*8]);
    #pragma unroll
    for (int n = 0; n < 4; n++)
      bfr[n] = *reinterpret_cast<const bf16x8*>(
          &Bs[(wc*64 + n*16 + c15)*32 + h4*8]);
    #pragma unroll
    for (int n = 0; n < 4; n++)
      #pragma unroll
      for (int m = 0; m < 4; m++)
        acc[n][m] = __builtin_amdgcn_mfma_f32_16x16x32_bf16(bfr[n], af[m], acc[n][m], 0, 0, 0);
    __syncthreads();
  }

  // swapped layout: row r = row0+wr*64+m*16+c15 ; col c = col0+wc*64+n*16+h4*4+i
  int rb = row0 + wr*64 + c15;
  int cb = col0 + wc*64 + h4*4;
  #pragma unroll
  for (int m = 0; m < 4; m++) {
    int r = rb + m*16;
    if constexpr (EPI == 0) {
      int b_ = r / NTOK, nn = r % NTOK;
      const size_t QKVSTRIDE = (size_t)BWIN*NHEAD*NTOK*HDHEAD;
      #pragma unroll
      for (int n = 0; n < 4; n++) {
        int c0 = cb + n*16;
        f32x4 v = acc[n][m];
        f32x4 b4 = *(const f32x4*)&bias[c0];
        int which = c0 / CDIM, rem = c0 - which*CDIM;
        int hh = rem >> 5, dd = rem & 31;
        float scl = (which == 0) ? ATTSCALE : 1.f;
        s16x4 o;
        #pragma unroll
        for (int i = 0; i < 4; i++) o[i] = f2bfs((v[i] + b4[i]) * scl);
        *(s16x4*)&outb[(size_t)which*QKVSTRIDE + (((size_t)b_*NHEAD+hh)*NTOK+nn)*HDHEAD + dd] = o;
      }
    } else if constexpr (EPI == 1) {
      int b_ = r / NTOK, nn = r % NTOK;
      int b = b_ >> 4, wi = b_ & 15, wh = wi >> 2, ww = wi & 3;
      int ii = nn / WSZ, jj = nn % WSZ;
      int hh = (wh*WSZ + ii + SSZ) % HDIM;
      int wcc = (ww*WSZ + jj + SSZ) % WDIM;
      size_t rr = ((size_t)b*LDIM + hh*WDIM + wcc) * CDIM;
      #pragma unroll
      for (int n = 0; n < 4; n++) {
        int c0 = cb + n*16;
        f32x4 v = acc[n][m];
        f32x4 b4 = *(const f32x4*)&bias[c0];
        f32x4 a4 = *(const f32x4*)&aux[rr + c0];
        s16x4 o;
        #pragma unroll
        for (int i = 0; i < 4; i++) o[i] = f2bfs(a4[i] + v[i] + b4[i]);
        *(s16x4*)&outb[rr + c0] = o;
      }
    } else if constexpr (EPI == 2) {
      #pragma unroll
      for (int n = 0; n < 4; n++) {
        int c0 = cb + n*16;
        f32x4 v = acc[n][m];
        f32x4 b4 = *(const f32x4*)&bias[c0];
        s16x4 o;
        #pragma unroll
        for (int i = 0; i < 4; i++) {
          float val = v[i] + b4[i];
          val = 0.5f * val * (1.0f + erff(val * 0.70710678118654752f));
          o[i] = f2bfs(val);
        }
        *(s16x4*)&outb[(size_t)r*HIDDIM + c0] = o;
      }
    } else {
      #pragma unroll
      for (int n = 0; n < 4; n++) {
        int c0 = cb + n*16;
        f32x4 v = acc[n][m];
        f32x4 b4 = *(const f32x4*)&bias[c0];
        s16x4 ab = *(const s16x4*)&auxb[(size_t)r*CDIM + c0];
        f32x4 o;
        #pragma unroll
        for (int i = 0; i < 4; i++) o[i] = v[i] + b4[i] + bfs2f(ab[i]);
        *(f32x4*)&outf[(size_t)r*CDIM + c0] = o;
      }
    }
  }
}

// ---------------- MFMA fused window attention ----------------
// barrier-hardened; dummy strip-slots guarded (wave-uniform); no-max softmax
// (scores bounded ~|2|; masked/-1e30 pad underflow to exactly 0)
__global__ __launch_bounds__(256) void k_attn_mfma(const bf16* __restrict__ q,
    const bf16* __restrict__ k, const bf16* __restrict__ v,
    const float* __restrict__ rt, bf16* __restrict__ out)
{
  __shared__ short  Ks[208*KROW];   // [m][k], rows 196..207 zero, padded stride
  __shared__ short  Vt[32*VROW];    // [d][m], cols 196..223 zero, padded stride
  __shared__ short  Ps[4][16*PROW]; // per-wave P strip [row][m], padded stride
  __shared__ float2 tab2[729];      // {bias, rscale} per rel-idx for this head
  __shared__ int    regv[208];

  int blk = blockIdx.x;
  int b_ = blk / NHEAD, head = blk % NHEAD;
  int tid = threadIdx.x, lane = tid & 63, wid = tid >> 6;
  int c15 = lane & 15, h4 = lane >> 4;

  // ---- staging ----
  const bf16* kp = k + (size_t)blk*NTOK*HDHEAD;
  const bf16* vp = v + (size_t)blk*NTOK*HDHEAD;
  for (int c = tid; c < 784; c += 256) {          // 196 rows x 4 chunks of 8
    int m = c >> 2, k8 = (c & 3) * 8;
    *(bf16x8*)&Ks[m*KROW + k8] = *(const bf16x8*)(kp + m*32 + k8);
    bf16x8 vv = *(const bf16x8*)(vp + m*32 + k8);
    #pragma unroll
    for (int j = 0; j < 8; j++) Vt[(k8+j)*VROW + m] = vv[j];
  }
  for (int e = tid; e < 12*KROW; e += 256) Ks[196*KROW + e] = 0;
  for (int e = tid; e < 32*28; e += 256) Vt[(e/28)*VROW + 196 + (e%28)] = 0;
  for (int e = tid; e < 729; e += 256)
    tab2[e] = make_float2(rt[e*2*NHEAD + head], rt[e*2*NHEAD + NHEAD + head]);
  {
    int wi = b_ & 15, wh = wi >> 2, ww = wi & 3;
    for (int e = tid; e < 208; e += 256) {
      int rv = 0;
      if (e < NTOK) {
        int i = e / WSZ, j = e % WSZ;
        int ha = wh*WSZ + i, wa = ww*WSZ + j;
        int rh = ha < (HDIM-WSZ) ? 0 : (ha < (HDIM-SSZ) ? 1 : 2);
        int rw = wa < (WDIM-WSZ) ? 0 : (wa < (WDIM-SSZ) ? 1 : 2);
        rv = rh*3 + rw;
      }
      regv[e] = rv;
    }
  }
  __syncthreads();

  // per-lane m-column constants (m = t*16 + c15)
  int   moff[13], mreg[13];
  float mpad[13];
  #pragma unroll
  for (int t = 0; t < 13; t++) {
    int m  = t*16 + c15;
    int mm = min(m, NTOK-1);
    moff[t] = (mm/WSZ)*27 + (mm%WSZ);
    mreg[t] = regv[mm];
    mpad[t] = (m >= NTOK) ? -1e30f : 0.f;
  }

  short* myP = &Ps[wid][0];
  // zero pad cols 208..223 once (never overwritten: softmax writes cols 0..207)
  #pragma unroll
  for (int i = 0; i < 4; i++) myP[(h4*4+i)*PROW + 208 + c15] = 0;

  bf16* op = out + (size_t)b_*NTOK*CDIM + head*HDHEAD;

  for (int t4 = 0; t4 < 4; t4++) {
    int s = t4*4 + wid;                 // 0..15; 13..15 dummy (guarded off)
    if (s < 13) {
      int qrow = min(s*16 + c15, NTOK-1);
      bf16x8 qf = *(const bf16x8*)(q + ((size_t)blk*NTOK + qrow)*HDHEAD + h4*8);

      f32x4 sc[13];
      #pragma unroll
      for (int t = 0; t < 13; t++) {
        bf16x8 kf = *(const bf16x8*)&Ks[(t*16 + c15)*KROW + h4*8];
        sc[t] = __builtin_amdgcn_mfma_f32_16x16x32_bf16(qf, kf, (f32x4){0.f,0.f,0.f,0.f}, 0, 0, 0);
      }

      #pragma unroll
      for (int i = 0; i < 4; i++) {
        int n  = s*16 + h4*4 + i;
        int nc = min(n, NTOK-1);
        int nbase = ((nc/WSZ) + 13)*27 + (nc%WSZ) + 13;
        int nreg  = regv[nc];
        float rr[13];
        float sum = 0.f;
        #pragma unroll
        for (int t = 0; t < 13; t++) {
          float2 hr = tab2[nbase - moff[t]];
          float sv = sc[t][i] + hr.x + ((mreg[t] != nreg) ? -100.f : 0.f) + mpad[t];
          float e = __expf(sv);          // no-max softmax: |sv| tiny or -> 0
          rr[t] = hr.y;
          sc[t][i] = e; sum += e;
        }
        #pragma unroll
        for (int o = 1; o < 16; o <<= 1) sum += __shfl_xor(sum, o);
        float inv = 1.f / sum;
        int prow = h4*4 + i;
        #pragma unroll
        for (int t = 0; t < 13; t++)
          myP[prow*PROW + t*16 + c15] = f2bfs(sc[t][i] * inv * rr[t]);  // short store
      }
    }

    __syncthreads();   // drain P ds_writes before PV ds_reads (all waves uniform)

    if (s < 13) {
      // PV: O[16 x 32] = P[16 x 224] @ Vt^T
      f32x4 o0 = {0.f,0.f,0.f,0.f}, o1 = {0.f,0.f,0.f,0.f};
      #pragma unroll
      for (int t7 = 0; t7 < 7; t7++) {
        bf16x8 pf = *(const bf16x8*)&myP[c15*PROW + t7*32 + h4*8];
        bf16x8 v0 = *(const bf16x8*)&Vt[c15*VROW + t7*32 + h4*8];
        bf16x8 v1 = *(const bf16x8*)&Vt[(16 + c15)*VROW + t7*32 + h4*8];
        o0 = __builtin_amdgcn_mfma_f32_16x16x32_bf16(pf, v0, o0, 0, 0, 0);
        o1 = __builtin_amdgcn_mfma_f32_16x16x32_bf16(pf, v1, o1, 0, 0, 0);
      }

      #pragma unroll
      for (int i = 0; i < 4; i++) {
        int n = s*16 + h4*4 + i;
        if (n < NTOK) {
          op[(size_t)n*CDIM + c15]      = __float2bfloat16(o0[i]);
          op[(size_t)n*CDIM + 16 + c15] = __float2bfloat16(o1[i]);
        }
      }
    }

    __syncthreads();   // PV reads done before next strip's P writes
  }
}

// ---------------- launch ----------------
extern "C" void kernel_launch(void* const* d_in, const int* in_sizes, int n_in,
                              void* d_out, int out_size, void* d_ws, size_t ws_size,
                              hipStream_t stream)
{
  const float* x      = (const float*)d_in[0];
  const float* n1w    = (const float*)d_in[1];
  const float* n1b    = (const float*)d_in[2];
  const float* qkv_w  = (const float*)d_in[3];
  const float* qkv_b  = (const float*)d_in[4];
  const float* proj_w = (const float*)d_in[5];
  const float* proj_b = (const float*)d_in[6];
  const float* rt     = (const float*)d_in[7];
  const float* n2w    = (const float*)d_in[8];
  const float* n2b    = (const float*)d_in[9];
  const float* fc1_w  = (const float*)d_in[10];
  const float* fc1_b  = (const float*)d_in[11];
  const float* fc2_w  = (const float*)d_in[12];
  const float* fc2_b  = (const float*)d_in[13];

  char* ws = (char*)d_ws;
  const size_t SZ_BF = (size_t)MROWS * CDIM * 2;   // 77,070,336 B
  // arena (total exactly 8*SZ_BF, proven footprint):
  //  R0 [0,1SZ):    xw -> attnout -> (after proj) wf1,wf2
  //  R1 [1SZ,4SZ):  qkv -> x2(bf16,[1SZ,2SZ)) + hln([2SZ,3SZ))
  //  R2 [4SZ,8SZ):  wq,wp (head) -> hid (overwrites dead wq/wp at fc1)
  bf16*  xw      = (bf16*)ws;
  bf16*  attnout = (bf16*)ws;
  bf16*  qkv     = (bf16*)(ws + SZ_BF);
  bf16*  x2b     = (bf16*)(ws + SZ_BF);
  bf16*  hln     = (bf16*)(ws + 2*SZ_BF);
  bf16*  hid     = (bf16*)(ws + 4*SZ_BF);
  const int NQKVW = 3*CDIM*CDIM;      // 442368
  const int NPROJW = CDIM*CDIM;       // 147456
  const int NFCW  = HIDDIM*CDIM;      // 589824
  bf16* wq  = (bf16*)(ws + 4*SZ_BF);  // lives in R2 until fc1 clobbers it
  bf16* wp  = wq + NQKVW;
  bf16* wf1 = (bf16*)ws;              // converted into R0 after proj GEMM
  bf16* wf2 = wf1 + NFCW;
  const size_t QKVSTRIDE = (size_t)BWIN*NHEAD*NTOK*HDHEAD;

  k_cvt<<<(NQKVW+255)/256, 256, 0, stream>>>(qkv_w, wq, NQKVW);
  k_cvt<<<(NPROJW+255)/256, 256, 0, stream>>>(proj_w, wp, NPROJW);

  k_ln<true, float><<<MROWS, 128, 0, stream>>>(x, n1w, n1b, xw);
  k_mgemm<CDIM, 0><<<dim3((3*CDIM)/128, MROWS/128), 256, 0, stream>>>(
      xw, wq, qkv_b, nullptr, nullptr, nullptr, qkv);
  k_attn_mfma<<<BWIN*NHEAD, 256, 0, stream>>>(
      qkv, qkv + QKVSTRIDE, qkv + 2*QKVSTRIDE, rt, attnout);
  k_mgemm<CDIM, 1><<<dim3(CDIM/128, MROWS/128), 256, 0, stream>>>(
      attnout, wp, proj_b, x, nullptr, nullptr, x2b);

  k_cvt<<<(NFCW+255)/256, 256, 0, stream>>>(fc1_w, wf1, NFCW);
  k_cvt<<<(NFCW+255)/256, 256, 0, stream>>>(fc2_w, wf2, NFCW);

  k_ln<false, bf16><<<MROWS, 128, 0, stream>>>(x2b, n2w, n2b, hln);
  k_mgemm<CDIM, 2><<<dim3(HIDDIM/128, MROWS/128), 256, 0, stream>>>(
      hln, wf1, fc1_b, nullptr, nullptr, nullptr, hid);
  k_mgemm<HIDDIM, 3><<<dim3(CDIM/128, MROWS/128), 256, 0, stream>>>(
      hid, wf2, fc2_b, nullptr, x2b, (float*)d_out, nullptr);
}

// Round 8
// 1086.902 us; speedup vs baseline: 7.3170x; 1.0363x over previous
//
#include <hip/hip_runtime.h>
#include <hip/hip_bf16.h>
#include <math.h>

// ---------------- problem constants ----------------
#define BDIM 32
#define HDIM 56
#define WDIM 56
#define CDIM 384
#define NHEAD 12
#define WSZ 14
#define SSZ 7
#define LDIM (HDIM*WDIM)        // 3136
#define NTOK (WSZ*WSZ)          // 196
#define HDHEAD (CDIM/NHEAD)     // 32
#define HIDDIM (4*CDIM)         // 1536
#define NWIN 16
#define BWIN (BDIM*NWIN)        // 512
#define MROWS (BDIM*LDIM)       // 100352 == BWIN*NTOK
#define EPSLN 1e-5f
#define ATTSCALE 0.17677669529663687f   // 32^-0.5

// padded LDS strides (shorts) for attention
#define KROW 40
#define VROW 232
#define PROW 232

typedef __hip_bfloat16 bf16;
typedef __attribute__((ext_vector_type(8))) short bf16x8;   // 8 bf16 = 4 VGPRs
typedef __attribute__((ext_vector_type(4))) short s16x4;    // 4 bf16 = 1 b64 store
typedef __attribute__((ext_vector_type(4))) float f32x4;

// async global->LDS, 16B per lane, wave-uniform LDS base
#define ASYNC16(gp, lp) __builtin_amdgcn_global_load_lds( \
    (__attribute__((address_space(1))) void*)(gp),        \
    (__attribute__((address_space(3))) void*)(lp), 16, 0, 0)

// float -> bf16 bit pattern as short (type-consistent with short LDS arrays)
static __device__ __forceinline__ short f2bfs(float x) {
  union { bf16 h; short s; } u; u.h = __float2bfloat16(x); return u.s;
}
static __device__ __forceinline__ float bfs2f(short s) {
  unsigned int u = ((unsigned int)(unsigned short)s) << 16;
  float f; __builtin_memcpy(&f, &u, 4); return f;
}
static __device__ __forceinline__ float tof(float x) { return x; }
static __device__ __forceinline__ float tof(bf16 x)  { return __bfloat162float(x); }

// ---------------- fp32 -> bf16 weight convert ----------------
__global__ __launch_bounds__(256) void k_cvt(const float* __restrict__ in,
                                             bf16* __restrict__ out, int n)
{
  int i = blockIdx.x * 256 + threadIdx.x;
  if (i < n) out[i] = __float2bfloat16(in[i]);
}

// ---------------- LN (+optional shift-roll + window partition) ----------------
template<bool WIN, typename TIN>
__global__ __launch_bounds__(128) void k_ln(const TIN* __restrict__ xin,
    const float* __restrict__ gw, const float* __restrict__ gb,
    bf16* __restrict__ out)
{
  int r = blockIdx.x;
  int t = threadIdx.x;
  const TIN* xp = xin + (size_t)r * CDIM;
  float v0 = tof(xp[t]), v1 = tof(xp[t+128]), v2 = tof(xp[t+256]);
  float s  = v0+v1+v2;
  float ss = v0*v0 + v1*v1 + v2*v2;
  #pragma unroll
  for (int o = 32; o > 0; o >>= 1) { s += __shfl_down(s, o); ss += __shfl_down(ss, o); }
  __shared__ float red[4];
  if ((t & 63) == 0) { red[(t>>6)*2] = s; red[(t>>6)*2+1] = ss; }
  __syncthreads();
  float mean = (red[0]+red[2]) * (1.0f/CDIM);
  float var  = (red[1]+red[3]) * (1.0f/CDIM) - mean*mean;
  float rstd = rsqrtf(var + EPSLN);

  size_t orow;
  if (WIN) {
    int b = r / LDIM, l = r % LDIM;
    int h = l / WDIM, w = l % WDIM;
    int h2 = (h + HDIM - SSZ) % HDIM, w2 = (w + WDIM - SSZ) % WDIM;
    int wh = h2 / WSZ, ii = h2 % WSZ, ww = w2 / WSZ, jj = w2 % WSZ;
    int b_ = b*NWIN + wh*4 + ww;
    int n  = ii*WSZ + jj;
    orow = ((size_t)b_*NTOK + n) * CDIM;
  } else {
    orow = (size_t)r * CDIM;
  }
  out[orow+t]     = __float2bfloat16((v0-mean)*rstd*gw[t]     + gb[t]);
  out[orow+t+128] = __float2bfloat16((v1-mean)*rstd*gw[t+128] + gb[t+128]);
  out[orow+t+256] = __float2bfloat16((v2-mean)*rstd*gw[t+256] + gb[t+256]);
}

// ---------------- MFMA GEMM: C = A(bf16,MxK) @ Wb(bf16,NCxK)^T ----------------
// Operand-SWAPPED MFMA (lane owns row + 4 consecutive cols) + vector epilogue.
// 1-D grid with XCD-bijective swizzle (nwg % 8 == 0) so N-tiles sharing an
// A-panel land on the same XCD L2. K-step 64 = two 128x32 sub-tiles staged
// behind ONE barrier pair (halves barrier-drain count vs BK=32).
// EPI 0: qkv scatter (+SCALE on q)   EPI 1: proj + window-reverse + residual(f32) -> bf16
// EPI 2: fc1 + exact gelu -> bf16    EPI 3: fc2 + bias + residual(bf16) -> f32
template<int KD, int EPI>
__global__ __launch_bounds__(256) void k_mgemm(
    const bf16* __restrict__ A, const bf16* __restrict__ Wb,
    const float* __restrict__ bias, const float* __restrict__ aux,
    const bf16* __restrict__ auxb,
    float* __restrict__ outf, bf16* __restrict__ outb, int gx)
{
  __shared__ short As[2][128*32];   // two K sub-tiles, 16 KB each pair
  __shared__ short Bs[2][128*32];
  int tid  = threadIdx.x;
  int lane = tid & 63, wid = tid >> 6;
  int c15 = lane & 15, h4 = lane >> 4;
  int wr = wid >> 1, wc = wid & 1;

  // XCD-bijective swizzle: XCD j (= bid%8) covers a contiguous tile chunk
  int nwg = gridDim.x, bid = blockIdx.x;
  int swz = (bid & 7) * (nwg >> 3) + (bid >> 3);
  int ty = swz / gx, tx = swz - ty * gx;
  int row0 = ty * 128, col0 = tx * 128;

  f32x4 acc[4][4] = {};          // [n][m]

  int srow[2];
  int skk = (lane & 3) * 8;
  #pragma unroll
  for (int s = 0; s < 2; s++) {
    int c = wid*2 + s;
    srow[s] = c*16 + (lane >> 2);
  }

  for (int k0 = 0; k0 < KD; k0 += 64) {
    #pragma unroll
    for (int s = 0; s < 2; s++) {
      int c = wid*2 + s;
      const bf16* ap = A  + (size_t)(row0 + srow[s])*KD + k0 + skk;
      const bf16* bp = Wb + (size_t)(col0 + srow[s])*KD + k0 + skk;
      ASYNC16(ap,      &As[0][c*512]);
      ASYNC16(bp,      &Bs[0][c*512]);
      ASYNC16(ap + 32, &As[1][c*512]);
      ASYNC16(bp + 32, &Bs[1][c*512]);
    }
    __syncthreads();

    #pragma unroll
    for (int half = 0; half < 2; half++) {
      bf16x8 af[4], bfr[4];
      #pragma unroll
      for (int m = 0; m < 4; m++)
        af[m] = *reinterpret_cast<const bf16x8*>(
            &As[half][(wr*64 + m*16 + c15)*32 + h4*8]);
      #pragma unroll
      for (int n = 0; n < 4; n++)
        bfr[n] = *reinterpret_cast<const bf16x8*>(
            &Bs[half][(wc*64 + n*16 + c15)*32 + h4*8]);
      #pragma unroll
      for (int n = 0; n < 4; n++)
        #pragma unroll
        for (int m = 0; m < 4; m++)
          acc[n][m] = __builtin_amdgcn_mfma_f32_16x16x32_bf16(bfr[n], af[m], acc[n][m], 0, 0, 0);
    }
    __syncthreads();
  }

  // swapped layout: row r = row0+wr*64+m*16+c15 ; col c = col0+wc*64+n*16+h4*4+i
  int rb = row0 + wr*64 + c15;
  int cb = col0 + wc*64 + h4*4;
  #pragma unroll
  for (int m = 0; m < 4; m++) {
    int r = rb + m*16;
    if constexpr (EPI == 0) {
      int b_ = r / NTOK, nn = r % NTOK;
      const size_t QKVSTRIDE = (size_t)BWIN*NHEAD*NTOK*HDHEAD;
      #pragma unroll
      for (int n = 0; n < 4; n++) {
        int c0 = cb + n*16;
        f32x4 v = acc[n][m];
        f32x4 b4 = *(const f32x4*)&bias[c0];
        int which = c0 / CDIM, rem = c0 - which*CDIM;
        int hh = rem >> 5, dd = rem & 31;
        float scl = (which == 0) ? ATTSCALE : 1.f;
        s16x4 o;
        #pragma unroll
        for (int i = 0; i < 4; i++) o[i] = f2bfs((v[i] + b4[i]) * scl);
        *(s16x4*)&outb[(size_t)which*QKVSTRIDE + (((size_t)b_*NHEAD+hh)*NTOK+nn)*HDHEAD + dd] = o;
      }
    } else if constexpr (EPI == 1) {
      int b_ = r / NTOK, nn = r % NTOK;
      int b = b_ >> 4, wi = b_ & 15, wh = wi >> 2, ww = wi & 3;
      int ii = nn / WSZ, jj = nn % WSZ;
      int hh = (wh*WSZ + ii + SSZ) % HDIM;
      int wcc = (ww*WSZ + jj + SSZ) % WDIM;
      size_t rr = ((size_t)b*LDIM + hh*WDIM + wcc) * CDIM;
      #pragma unroll
      for (int n = 0; n < 4; n++) {
        int c0 = cb + n*16;
        f32x4 v = acc[n][m];
        f32x4 b4 = *(const f32x4*)&bias[c0];
        f32x4 a4 = *(const f32x4*)&aux[rr + c0];
        s16x4 o;
        #pragma unroll
        for (int i = 0; i < 4; i++) o[i] = f2bfs(a4[i] + v[i] + b4[i]);
        *(s16x4*)&outb[rr + c0] = o;
      }
    } else if constexpr (EPI == 2) {
      #pragma unroll
      for (int n = 0; n < 4; n++) {
        int c0 = cb + n*16;
        f32x4 v = acc[n][m];
        f32x4 b4 = *(const f32x4*)&bias[c0];
        s16x4 o;
        #pragma unroll
        for (int i = 0; i < 4; i++) {
          float val = v[i] + b4[i];
          val = 0.5f * val * (1.0f + erff(val * 0.70710678118654752f));
          o[i] = f2bfs(val);
        }
        *(s16x4*)&outb[(size_t)r*HIDDIM + c0] = o;
      }
    } else {
      #pragma unroll
      for (int n = 0; n < 4; n++) {
        int c0 = cb + n*16;
        f32x4 v = acc[n][m];
        f32x4 b4 = *(const f32x4*)&bias[c0];
        s16x4 ab = *(const s16x4*)&auxb[(size_t)r*CDIM + c0];
        f32x4 o;
        #pragma unroll
        for (int i = 0; i < 4; i++) o[i] = v[i] + b4[i] + bfs2f(ab[i]);
        *(f32x4*)&outf[(size_t)r*CDIM + c0] = o;
      }
    }
  }
}

// ---------------- MFMA fused window attention ----------------
// barrier-hardened; dummy strip-slots guarded (wave-uniform); no-max softmax
// (scores bounded ~|2|; masked/-1e30 pad underflow to exactly 0)
__global__ __launch_bounds__(256) void k_attn_mfma(const bf16* __restrict__ q,
    const bf16* __restrict__ k, const bf16* __restrict__ v,
    const float* __restrict__ rt, bf16* __restrict__ out)
{
  __shared__ short  Ks[208*KROW];   // [m][k], rows 196..207 zero, padded stride
  __shared__ short  Vt[32*VROW];    // [d][m], cols 196..223 zero, padded stride
  __shared__ short  Ps[4][16*PROW]; // per-wave P strip [row][m], padded stride
  __shared__ float2 tab2[729];      // {bias, rscale} per rel-idx for this head
  __shared__ int    regv[208];

  int blk = blockIdx.x;
  int b_ = blk / NHEAD, head = blk % NHEAD;
  int tid = threadIdx.x, lane = tid & 63, wid = tid >> 6;
  int c15 = lane & 15, h4 = lane >> 4;

  // ---- staging ----
  const bf16* kp = k + (size_t)blk*NTOK*HDHEAD;
  const bf16* vp = v + (size_t)blk*NTOK*HDHEAD;
  for (int c = tid; c < 784; c += 256) {          // 196 rows x 4 chunks of 8
    int m = c >> 2, k8 = (c & 3) * 8;
    *(bf16x8*)&Ks[m*KROW + k8] = *(const bf16x8*)(kp + m*32 + k8);
    bf16x8 vv = *(const bf16x8*)(vp + m*32 + k8);
    #pragma unroll
    for (int j = 0; j < 8; j++) Vt[(k8+j)*VROW + m] = vv[j];
  }
  for (int e = tid; e < 12*KROW; e += 256) Ks[196*KROW + e] = 0;
  for (int e = tid; e < 32*28; e += 256) Vt[(e/28)*VROW + 196 + (e%28)] = 0;
  for (int e = tid; e < 729; e += 256)
    tab2[e] = make_float2(rt[e*2*NHEAD + head], rt[e*2*NHEAD + NHEAD + head]);
  {
    int wi = b_ & 15, wh = wi >> 2, ww = wi & 3;
    for (int e = tid; e < 208; e += 256) {
      int rv = 0;
      if (e < NTOK) {
        int i = e / WSZ, j = e % WSZ;
        int ha = wh*WSZ + i, wa = ww*WSZ + j;
        int rh = ha < (HDIM-WSZ) ? 0 : (ha < (HDIM-SSZ) ? 1 : 2);
        int rw = wa < (WDIM-WSZ) ? 0 : (wa < (WDIM-SSZ) ? 1 : 2);
        rv = rh*3 + rw;
      }
      regv[e] = rv;
    }
  }
  __syncthreads();

  // per-lane m-column constants (m = t*16 + c15)
  int   moff[13], mreg[13];
  float mpad[13];
  #pragma unroll
  for (int t = 0; t < 13; t++) {
    int m  = t*16 + c15;
    int mm = min(m, NTOK-1);
    moff[t] = (mm/WSZ)*27 + (mm%WSZ);
    mreg[t] = regv[mm];
    mpad[t] = (m >= NTOK) ? -1e30f : 0.f;
  }

  short* myP = &Ps[wid][0];
  // zero pad cols 208..223 once (never overwritten: softmax writes cols 0..207)
  #pragma unroll
  for (int i = 0; i < 4; i++) myP[(h4*4+i)*PROW + 208 + c15] = 0;

  bf16* op = out + (size_t)b_*NTOK*CDIM + head*HDHEAD;

  for (int t4 = 0; t4 < 4; t4++) {
    int s = t4*4 + wid;                 // 0..15; 13..15 dummy (guarded off)
    if (s < 13) {
      int qrow = min(s*16 + c15, NTOK-1);
      bf16x8 qf = *(const bf16x8*)(q + ((size_t)blk*NTOK + qrow)*HDHEAD + h4*8);

      f32x4 sc[13];
      #pragma unroll
      for (int t = 0; t < 13; t++) {
        bf16x8 kf = *(const bf16x8*)&Ks[(t*16 + c15)*KROW + h4*8];
        sc[t] = __builtin_amdgcn_mfma_f32_16x16x32_bf16(qf, kf, (f32x4){0.f,0.f,0.f,0.f}, 0, 0, 0);
      }

      #pragma unroll
      for (int i = 0; i < 4; i++) {
        int n  = s*16 + h4*4 + i;
        int nc = min(n, NTOK-1);
        int nbase = ((nc/WSZ) + 13)*27 + (nc%WSZ) + 13;
        int nreg  = regv[nc];
        float rr[13];
        float sum = 0.f;
        #pragma unroll
        for (int t = 0; t < 13; t++) {
          float2 hr = tab2[nbase - moff[t]];
          float sv = sc[t][i] + hr.x + ((mreg[t] != nreg) ? -100.f : 0.f) + mpad[t];
          float e = __expf(sv);          // no-max softmax: |sv| tiny or -> 0
          rr[t] = hr.y;
          sc[t][i] = e; sum += e;
        }
        #pragma unroll
        for (int o = 1; o < 16; o <<= 1) sum += __shfl_xor(sum, o);
        float inv = 1.f / sum;
        int prow = h4*4 + i;
        #pragma unroll
        for (int t = 0; t < 13; t++)
          myP[prow*PROW + t*16 + c15] = f2bfs(sc[t][i] * inv * rr[t]);  // short store
      }
    }

    __syncthreads();   // drain P ds_writes before PV ds_reads (all waves uniform)

    if (s < 13) {
      // PV: O[16 x 32] = P[16 x 224] @ Vt^T
      f32x4 o0 = {0.f,0.f,0.f,0.f}, o1 = {0.f,0.f,0.f,0.f};
      #pragma unroll
      for (int t7 = 0; t7 < 7; t7++) {
        bf16x8 pf = *(const bf16x8*)&myP[c15*PROW + t7*32 + h4*8];
        bf16x8 v0 = *(const bf16x8*)&Vt[c15*VROW + t7*32 + h4*8];
        bf16x8 v1 = *(const bf16x8*)&Vt[(16 + c15)*VROW + t7*32 + h4*8];
        o0 = __builtin_amdgcn_mfma_f32_16x16x32_bf16(pf, v0, o0, 0, 0, 0);
        o1 = __builtin_amdgcn_mfma_f32_16x16x32_bf16(pf, v1, o1, 0, 0, 0);
      }

      #pragma unroll
      for (int i = 0; i < 4; i++) {
        int n = s*16 + h4*4 + i;
        if (n < NTOK) {
          op[(size_t)n*CDIM + c15]      = __float2bfloat16(o0[i]);
          op[(size_t)n*CDIM + 16 + c15] = __float2bfloat16(o1[i]);
        }
      }
    }

    __syncthreads();   // PV reads done before next strip's P writes
  }
}

// ---------------- launch ----------------
extern "C" void kernel_launch(void* const* d_in, const int* in_sizes, int n_in,
                              void* d_out, int out_size, void* d_ws, size_t ws_size,
                              hipStream_t stream)
{
  const float* x      = (const float*)d_in[0];
  const float* n1w    = (const float*)d_in[1];
  const float* n1b    = (const float*)d_in[2];
  const float* qkv_w  = (const float*)d_in[3];
  const float* qkv_b  = (const float*)d_in[4];
  const float* proj_w = (const float*)d_in[5];
  const float* proj_b = (const float*)d_in[6];
  const float* rt     = (const float*)d_in[7];
  const float* n2w    = (const float*)d_in[8];
  const float* n2b    = (const float*)d_in[9];
  const float* fc1_w  = (const float*)d_in[10];
  const float* fc1_b  = (const float*)d_in[11];
  const float* fc2_w  = (const float*)d_in[12];
  const float* fc2_b  = (const float*)d_in[13];

  char* ws = (char*)d_ws;
  const size_t SZ_BF = (size_t)MROWS * CDIM * 2;   // 77,070,336 B
  // arena (total exactly 8*SZ_BF, proven footprint):
  //  R0 [0,1SZ):    xw -> attnout -> (after proj) wf1,wf2
  //  R1 [1SZ,4SZ):  qkv -> x2(bf16,[1SZ,2SZ)) + hln([2SZ,3SZ))
  //  R2 [4SZ,8SZ):  wq,wp (head) -> hid (overwrites dead wq/wp at fc1)
  bf16*  xw      = (bf16*)ws;
  bf16*  attnout = (bf16*)ws;
  bf16*  qkv     = (bf16*)(ws + SZ_BF);
  bf16*  x2b     = (bf16*)(ws + SZ_BF);
  bf16*  hln     = (bf16*)(ws + 2*SZ_BF);
  bf16*  hid     = (bf16*)(ws + 4*SZ_BF);
  const int NQKVW = 3*CDIM*CDIM;      // 442368
  const int NPROJW = CDIM*CDIM;       // 147456
  const int NFCW  = HIDDIM*CDIM;      // 589824
  bf16* wq  = (bf16*)(ws + 4*SZ_BF);  // lives in R2 until fc1 clobbers it
  bf16* wp  = wq + NQKVW;
  bf16* wf1 = (bf16*)ws;              // converted into R0 after proj GEMM
  bf16* wf2 = wf1 + NFCW;
  const size_t QKVSTRIDE = (size_t)BWIN*NHEAD*NTOK*HDHEAD;

  k_cvt<<<(NQKVW+255)/256, 256, 0, stream>>>(qkv_w, wq, NQKVW);
  k_cvt<<<(NPROJW+255)/256, 256, 0, stream>>>(proj_w, wp, NPROJW);

  k_ln<true, float><<<MROWS, 128, 0, stream>>>(x, n1w, n1b, xw);
  k_mgemm<CDIM, 0><<<9*(MROWS/128), 256, 0, stream>>>(
      xw, wq, qkv_b, nullptr, nullptr, nullptr, qkv, 9);
  k_attn_mfma<<<BWIN*NHEAD, 256, 0, stream>>>(
      qkv, qkv + QKVSTRIDE, qkv + 2*QKVSTRIDE, rt, attnout);
  k_mgemm<CDIM, 1><<<3*(MROWS/128), 256, 0, stream>>>(
      attnout, wp, proj_b, x, nullptr, nullptr, x2b, 3);

  k_cvt<<<(NFCW+255)/256, 256, 0, stream>>>(fc1_w, wf1, NFCW);
  k_cvt<<<(NFCW+255)/256, 256, 0, stream>>>(fc2_w, wf2, NFCW);

  k_ln<false, bf16><<<MROWS, 128, 0, stream>>>(x2b, n2w, n2b, hln);
  k_mgemm<CDIM, 2><<<12*(MROWS/128), 256, 0, stream>>>(
      hln, wf1, fc1_b, nullptr, nullptr, nullptr, hid, 12);
  k_mgemm<HIDDIM, 3><<<3*(MROWS/128), 256, 0, stream>>>(
      hid, wf2, fc2_b, nullptr, x2b, (float*)d_out, nullptr, 3);
}